// Round 1
// baseline (2184.277 us; speedup 1.0000x reference)
//
#include <hip/hip_runtime.h>
#include <hip/hip_bf16.h>

#define N_NODES 100000
#define E_EDGES 800000
#define E2 (E_EDGES + N_NODES)   // 900000 edges incl. self loops
#define FIN 128
#define HD 64
#define NH 8
#define NG 128
#define NC 10
#define SLOPE 0.2f

__device__ __forceinline__ float lrelu(float x) { return x > 0.f ? x : SLOPE * x; }

__device__ __forceinline__ void atomicMaxFloat(float* addr, float val) {
    // classic signed/unsigned encoding trick; init bits must be 0xFFFFFFFF (or -inf)
    if (val >= 0.f) atomicMax((int*)addr, __float_as_int(val));
    else            atomicMin((unsigned int*)addr, __float_as_uint(val));
}

// ---------------------------------------------------------------------------
// Generic node GEMM: out[n][j] = sum_k in[n][k] * W[k][j]  (+ epilogues)
// MODE 0: plain.  MODE 1: also es/ed head dots (KOUT must be 64).
// MODE 2: multiply row result by scale[n].
// blockDim = 256.
// ---------------------------------------------------------------------------
template<int KIN, int KOUT, int MODE>
__global__ void gemm_node(const float* __restrict__ in, const float* __restrict__ W,
                          float* __restrict__ out, const float* __restrict__ scale,
                          const float* __restrict__ a_s, const float* __restrict__ a_d,
                          float* __restrict__ es, float* __restrict__ ed, int nrows)
{
    __shared__ float Ws[KIN * KOUT];
    for (int i = threadIdx.x; i < KIN * KOUT; i += 256) Ws[i] = W[i];
    __syncthreads();
    int idx = blockIdx.x * 256 + threadIdx.x;
    int n = idx / KOUT;
    int j = idx % KOUT;
    if (n >= nrows) return;
    const float* row = in + (size_t)n * KIN;
    float acc = 0.f;
#pragma unroll 8
    for (int k = 0; k < KIN; ++k) acc = fmaf(row[k], Ws[k * KOUT + j], acc);
    if (MODE == 2) acc *= scale[n];
    out[(size_t)n * KOUT + j] = acc;
    if (MODE == 1) {
        // j = h*8 + d ; reduce over d within aligned groups of 8 lanes
        float pes = acc * a_s[j];
        float ped = acc * a_d[j];
#pragma unroll
        for (int o = 1; o < 8; o <<= 1) {
            pes += __shfl_xor(pes, o, 64);
            ped += __shfl_xor(ped, o, 64);
        }
        if ((j & 7) == 0) {
            es[n * NH + (j >> 3)] = pes;
            ed[n * NH + (j >> 3)] = ped;
        }
    }
}

// ---------------------------------------------------------------------------
// GAT edge passes (thread per (edge, head))
// ---------------------------------------------------------------------------
__global__ void gat_edge_max(const int* __restrict__ ei, const float* __restrict__ es,
                             const float* __restrict__ ed, float* __restrict__ m)
{
    int idx = blockIdx.x * 256 + threadIdx.x;
    if (idx >= E2 * NH) return;
    int e = idx >> 3, h = idx & 7;
    int s, d;
    if (e < E_EDGES) { s = ei[e]; d = ei[E_EDGES + e]; } else { s = d = e - E_EDGES; }
    float l = lrelu(es[s * NH + h] + ed[d * NH + h]);
    atomicMaxFloat(&m[d * NH + h], l);
}

__global__ void gat_edge_sum(const int* __restrict__ ei, const float* __restrict__ es,
                             const float* __restrict__ ed, const float* __restrict__ m,
                             float* __restrict__ den)
{
    int idx = blockIdx.x * 256 + threadIdx.x;
    if (idx >= E2 * NH) return;
    int e = idx >> 3, h = idx & 7;
    int s, d;
    if (e < E_EDGES) { s = ei[e]; d = ei[E_EDGES + e]; } else { s = d = e - E_EDGES; }
    float l = lrelu(es[s * NH + h] + ed[d * NH + h]);
    float ex = expf(l - m[d * NH + h]);
    atomicAdd(&den[d * NH + h], ex);
}

// wave (64 lanes = 64 features) per edge
__global__ void gat_edge_agg(const int* __restrict__ ei, const float* __restrict__ es,
                             const float* __restrict__ ed, const float* __restrict__ m,
                             const float* __restrict__ den, const float* __restrict__ hsrc,
                             float* __restrict__ out)
{
    int e = blockIdx.x * 4 + (threadIdx.x >> 6);
    int f = threadIdx.x & 63;
    if (e >= E2) return;
    int s, d;
    if (e < E_EDGES) { s = ei[e]; d = ei[E_EDGES + e]; } else { s = d = e - E_EDGES; }
    int h = f >> 3;
    float l = lrelu(es[s * NH + h] + ed[d * NH + h]);
    float ex = expf(l - m[d * NH + h]);
    float alpha = ex / (den[d * NH + h] + 1e-16f);
    atomicAdd(&out[(size_t)d * HD + f], hsrc[(size_t)s * HD + f] * alpha);
}

// elementwise: buf += bias ; optional ELU
__global__ void bias_act(float* __restrict__ buf, const float* __restrict__ b, int elu)
{
    int i = blockIdx.x * 256 + threadIdx.x;
    if (i >= N_NODES * HD) return;
    float v = buf[i] + b[i & 63];
    if (elu) v = v > 0.f ? v : (expf(v) - 1.f);
    buf[i] = v;
}

// ---------------------------------------------------------------------------
// node attention -> alpha_c, alpha_t   (wave per node)
// ---------------------------------------------------------------------------
__global__ void node_att(const float* __restrict__ H, const float* __restrict__ w1,
                         const float* __restrict__ b1, const float* __restrict__ w2,
                         const float* __restrict__ b2, float* __restrict__ ac,
                         float* __restrict__ at)
{
    int n = blockIdx.x * 4 + (threadIdx.x >> 6);
    int lane = threadIdx.x & 63;
    if (n >= N_NODES) return;
    const float* row = H + (size_t)n * HD;
    float hid = 0.f;
    if (lane < 32) {
        float a = b1[lane];
#pragma unroll 8
        for (int k = 0; k < HD; ++k) a = fmaf(row[k], w1[k * 32 + lane], a);
        hid = fmaxf(a, 0.f);
    }
    float p0 = lane < 32 ? hid * w2[lane * 2 + 0] : 0.f;
    float p1 = lane < 32 ? hid * w2[lane * 2 + 1] : 0.f;
#pragma unroll
    for (int o = 1; o < 64; o <<= 1) { p0 += __shfl_xor(p0, o, 64); p1 += __shfl_xor(p1, o, 64); }
    if (lane == 0) {
        float z0 = p0 + b2[0], z1 = p1 + b2[1];
        float mx = fmaxf(z0, z1);
        float e0 = expf(z0 - mx), e1 = expf(z1 - mx);
        float ssum = e0 + e1;
        ac[n] = e0 / ssum;
        at[n] = e1 / ssum;
    }
}

// ---------------------------------------------------------------------------
// edge attention -> beta_c, beta_t   (wave per original edge)
// hidden = relu(P1[src] + P2[dst] + b1)
// ---------------------------------------------------------------------------
__global__ void edge_att(const int* __restrict__ ei, const float* __restrict__ P1,
                         const float* __restrict__ P2, const float* __restrict__ b1,
                         const float* __restrict__ w2, const float* __restrict__ b2,
                         float* __restrict__ bc, float* __restrict__ bt)
{
    int e = blockIdx.x * 4 + (threadIdx.x >> 6);
    int j = threadIdx.x & 63;
    if (e >= E_EDGES) return;
    int s = ei[e], d = ei[E_EDGES + e];
    float hd = P1[(size_t)s * HD + j] + P2[(size_t)d * HD + j] + b1[j];
    hd = fmaxf(hd, 0.f);
    float p0 = hd * w2[j * 2 + 0];
    float p1 = hd * w2[j * 2 + 1];
#pragma unroll
    for (int o = 1; o < 64; o <<= 1) { p0 += __shfl_xor(p0, o, 64); p1 += __shfl_xor(p1, o, 64); }
    if (j == 0) {
        float z0 = p0 + b2[0], z1 = p1 + b2[1];
        float mx = fmaxf(z0, z1);
        float e0 = expf(z0 - mx), e1 = expf(z1 - mx);
        float ssum = e0 + e1;
        bc[e] = e0 / ssum;
        bt[e] = e1 / ssum;
    }
}

// ---------------------------------------------------------------------------
// GCN degree / norm / aggregate
// ---------------------------------------------------------------------------
__global__ void gcn_deg(const int* __restrict__ ei, const float* __restrict__ bc,
                        const float* __restrict__ bt, float* __restrict__ degc,
                        float* __restrict__ degt)
{
    int e = blockIdx.x * 256 + threadIdx.x;
    if (e >= E2) return;
    int d = e < E_EDGES ? ei[E_EDGES + e] : e - E_EDGES;
    float wc = e < E_EDGES ? bc[e] : 1.f;
    float wt = e < E_EDGES ? bt[e] : 1.f;
    atomicAdd(&degc[d], wc);
    atomicAdd(&degt[d], wt);
}

__global__ void deg_to_dis(float* __restrict__ degc, float* __restrict__ degt)
{
    int n = blockIdx.x * 256 + threadIdx.x;
    if (n >= N_NODES) return;
    float v = degc[n];
    degc[n] = v > 0.f ? rsqrtf(fmaxf(v, 1e-20f)) : 0.f;
    v = degt[n];
    degt[n] = v > 0.f ? rsqrtf(fmaxf(v, 1e-20f)) : 0.f;
}

__global__ void gcn_agg(const int* __restrict__ ei, const float* __restrict__ pre,
                        const float* __restrict__ dis, const float* __restrict__ beta,
                        float* __restrict__ out)
{
    int e = blockIdx.x * 4 + (threadIdx.x >> 6);
    int f = threadIdx.x & 63;
    if (e >= E2) return;
    int s, d; float w;
    if (e < E_EDGES) { s = ei[e]; d = ei[E_EDGES + e]; w = beta[e]; }
    else             { s = d = e - E_EDGES; w = 1.f; }
    float norm = dis[s] * w * dis[d];
    atomicAdd(&out[(size_t)d * HD + f], pre[(size_t)s * HD + f] * norm);
}

// ---------------------------------------------------------------------------
// readout: segment sum of Gagg rows by sorted `batch` -> S[g][64], counts
// wave per chunk of 128 consecutive nodes; run-accumulate before atomics
// ---------------------------------------------------------------------------
__global__ void readout(const float* __restrict__ Gagg, const int* __restrict__ batch,
                        float* __restrict__ S, float* __restrict__ cnt, int do_cnt)
{
    int chunk = blockIdx.x * 4 + (threadIdx.x >> 6);
    int lane = threadIdx.x & 63;
    int n0 = chunk * 128;
    if (n0 >= N_NODES) return;
    int n1 = n0 + 128; if (n1 > N_NODES) n1 = N_NODES;
    int gp = batch[n0];
    float acc = 0.f; int rc = 0;
    for (int n = n0; n < n1; ++n) {
        int g = batch[n];
        if (g != gp) {
            atomicAdd(&S[gp * 64 + lane], acc);
            if (do_cnt && lane == 0) atomicAdd(&cnt[gp], (float)rc);
            acc = 0.f; rc = 0; gp = g;
        }
        acc += Gagg[(size_t)n * 64 + lane];
        ++rc;
    }
    atomicAdd(&S[gp * 64 + lane], acc);
    if (do_cnt && lane == 0) atomicAdd(&cnt[gp], (float)rc);
}

// ---------------------------------------------------------------------------
// final per-graph: hGc/hGt + the three classifier MLPs. one 64-thread block/graph
// hGc = (S_c + cnt*gc_b) @ rc_w + cnt*rc_b
// ---------------------------------------------------------------------------
__global__ void final_head(const float* __restrict__ S_c, const float* __restrict__ S_t,
                           const float* __restrict__ cnt,
                           const float* __restrict__ gc_b, const float* __restrict__ gt_b,
                           const float* __restrict__ rc_w, const float* __restrict__ rc_b,
                           const float* __restrict__ rt_w, const float* __restrict__ rt_b,
                           const float* __restrict__ cc_w1, const float* __restrict__ cc_b1,
                           const float* __restrict__ cc_w2, const float* __restrict__ cc_b2,
                           const float* __restrict__ ct_w1, const float* __restrict__ ct_b1,
                           const float* __restrict__ ct_w2, const float* __restrict__ ct_b2,
                           const float* __restrict__ cm_w1, const float* __restrict__ cm_b1,
                           const float* __restrict__ cm_w2, const float* __restrict__ cm_b2,
                           float* __restrict__ out)
{
    int g = blockIdx.x;
    int j = threadIdx.x;           // 64 threads = 1 wave
    __shared__ float sc[64], st[64], hgc[64], hgt[64], hid[64];
    float c = cnt[g];
    sc[j] = S_c[g * 64 + j] + c * gc_b[j];
    st[j] = S_t[g * 64 + j] + c * gt_b[j];
    __syncthreads();
    float ac = c * rc_b[j], at2 = c * rt_b[j];
#pragma unroll 8
    for (int k = 0; k < 64; ++k) {
        ac  = fmaf(sc[k], rc_w[k * 64 + j], ac);
        at2 = fmaf(st[k], rt_w[k * 64 + j], at2);
    }
    hgc[j] = ac; hgt[j] = at2;
    out[3840 + g * 64 + j]  = ac;    // hGc
    out[12032 + g * 64 + j] = at2;   // hGt
    __syncthreads();
    // zc
    float hv = 0.f;
    if (j < 32) {
        float a = cc_b1[j];
#pragma unroll 8
        for (int k = 0; k < 64; ++k) a = fmaf(hgc[k], cc_w1[k * 32 + j], a);
        hv = fmaxf(a, 0.f);
    }
    hid[j] = hv;
    __syncthreads();
    if (j < NC) {
        float a = cc_b2[j];
#pragma unroll
        for (int k = 0; k < 32; ++k) a = fmaf(hid[k], cc_w2[k * NC + j], a);
        out[g * NC + j] = a;         // zc
    }
    __syncthreads();
    // zt
    hv = 0.f;
    if (j < 32) {
        float a = ct_b1[j];
#pragma unroll 8
        for (int k = 0; k < 64; ++k) a = fmaf(hgt[k], ct_w1[k * 32 + j], a);
        hv = fmaxf(a, 0.f);
    }
    hid[j] = hv;
    __syncthreads();
    if (j < NC) {
        float a = ct_b2[j];
#pragma unroll
        for (int k = 0; k < 32; ++k) a = fmaf(hid[k], ct_w2[k * NC + j], a);
        out[1280 + g * NC + j] = a;  // zt
    }
    __syncthreads();
    // zp: h_comb = [hGc, hGt] (128) -> cm_w1 (128x64) -> relu -> cm_w2 (64x10)
    {
        float a = cm_b1[j];
#pragma unroll 8
        for (int k = 0; k < 64; ++k) {
            a = fmaf(hgc[k], cm_w1[k * 64 + j], a);
            a = fmaf(hgt[k], cm_w1[(64 + k) * 64 + j], a);
        }
        hid[j] = fmaxf(a, 0.f);
    }
    __syncthreads();
    if (j < NC) {
        float a = cm_b2[j];
#pragma unroll 8
        for (int k = 0; k < 64; ++k) a = fmaf(hid[k], cm_w2[k * NC + j], a);
        out[2560 + g * NC + j] = a;  // zp
    }
}

// ---------------------------------------------------------------------------
extern "C" void kernel_launch(void* const* d_in, const int* in_sizes, int n_in,
                              void* d_out, int out_size, void* d_ws, size_t ws_size,
                              hipStream_t stream)
{
    const float* x     = (const float*)d_in[0];
    const int*   ei    = (const int*)d_in[1];
    const int*   batch = (const int*)d_in[2];
    const float* W1    = (const float*)d_in[3];
    const float* as1   = (const float*)d_in[4];
    const float* ad1   = (const float*)d_in[5];
    const float* b1    = (const float*)d_in[6];
    const float* W2    = (const float*)d_in[7];
    const float* as2   = (const float*)d_in[8];
    const float* ad2   = (const float*)d_in[9];
    const float* b2    = (const float*)d_in[10];
    const float* na_w1 = (const float*)d_in[11];
    const float* na_b1 = (const float*)d_in[12];
    const float* na_w2 = (const float*)d_in[13];
    const float* na_b2 = (const float*)d_in[14];
    const float* ea_w1 = (const float*)d_in[15];
    const float* ea_b1 = (const float*)d_in[16];
    const float* ea_w2 = (const float*)d_in[17];
    const float* ea_b2 = (const float*)d_in[18];
    const float* gc_w  = (const float*)d_in[19];
    const float* gc_b  = (const float*)d_in[20];
    const float* gt_w  = (const float*)d_in[21];
    const float* gt_b  = (const float*)d_in[22];
    const float* rc_w  = (const float*)d_in[23];
    const float* rc_b  = (const float*)d_in[24];
    const float* rt_w  = (const float*)d_in[25];
    const float* rt_b  = (const float*)d_in[26];
    const float* cc_w1 = (const float*)d_in[27];
    const float* cc_b1 = (const float*)d_in[28];
    const float* cc_w2 = (const float*)d_in[29];
    const float* cc_b2 = (const float*)d_in[30];
    const float* ct_w1 = (const float*)d_in[31];
    const float* ct_b1 = (const float*)d_in[32];
    const float* ct_w2 = (const float*)d_in[33];
    const float* ct_b2 = (const float*)d_in[34];
    const float* cm_w1 = (const float*)d_in[35];
    const float* cm_b1 = (const float*)d_in[36];
    const float* cm_w2 = (const float*)d_in[37];
    const float* cm_b2 = (const float*)d_in[38];
    float* out = (float*)d_out;

    // workspace layout (floats)
    float* ws = (float*)d_ws;
    size_t o = 0;
    const size_t nf = (size_t)N_NODES * HD;
    float* T0  = ws + o; o += nf;              // transform out / P2 / pre
    float* T1  = ws + o; o += nf;              // agg1/H1 / P1 / gcn agg
    float* T2  = ws + o; o += nf;              // agg2 -> H (persists)
    float* es  = ws + o; o += (size_t)N_NODES * NH;
    float* ed  = ws + o; o += (size_t)N_NODES * NH;
    float* m   = ws + o; o += (size_t)N_NODES * NH;
    float* den = ws + o; o += (size_t)N_NODES * NH;
    float* ac  = ws + o; o += N_NODES;
    float* at  = ws + o; o += N_NODES;
    float* bc  = ws + o; o += E_EDGES;
    float* bt  = ws + o; o += E_EDGES;
    float* degc = ws + o; o += N_NODES;        // degc,degt adjacent -> one memset
    float* degt = ws + o; o += N_NODES;
    float* S_c  = ws + o; o += NG * 64;        // S_c,S_t,cnt adjacent -> one memset
    float* S_t  = ws + o; o += NG * 64;
    float* cntf = ws + o; o += NG;

    const int GEMM_BLKS = N_NODES * 64 / 256;      // 25000
    const int EH_BLKS   = (E2 * NH + 255) / 256;   // 28125
    const int EW_BLKS   = E2 / 4;                  // 225000 (exact)
    const int EA_BLKS   = E_EDGES / 4;             // 200000 (exact)
    const int NA_BLKS   = N_NODES / 4;             // 25000 (exact)
    const int RO_BLKS   = ((N_NODES + 127) / 128 + 3) / 4;  // 196

    // ---------------- GAT layer 1 ----------------
    hipMemsetAsync(m,   0xFF, (size_t)N_NODES * NH * 4, stream);
    hipMemsetAsync(den, 0,    (size_t)N_NODES * NH * 4, stream);
    hipMemsetAsync(T1,  0,    nf * 4, stream);
    gemm_node<FIN, 64, 1><<<GEMM_BLKS, 256, 0, stream>>>(x, W1, T0, nullptr, as1, ad1, es, ed, N_NODES);
    gat_edge_max<<<EH_BLKS, 256, 0, stream>>>(ei, es, ed, m);
    gat_edge_sum<<<EH_BLKS, 256, 0, stream>>>(ei, es, ed, m, den);
    gat_edge_agg<<<EW_BLKS, 256, 0, stream>>>(ei, es, ed, m, den, T0, T1);
    bias_act<<<GEMM_BLKS, 256, 0, stream>>>(T1, b1, 1);    // H1 = elu(agg + b1)

    // ---------------- GAT layer 2 ----------------
    hipMemsetAsync(m,   0xFF, (size_t)N_NODES * NH * 4, stream);
    hipMemsetAsync(den, 0,    (size_t)N_NODES * NH * 4, stream);
    hipMemsetAsync(T2,  0,    nf * 4, stream);
    gemm_node<64, 64, 1><<<GEMM_BLKS, 256, 0, stream>>>(T1, W2, T0, nullptr, as2, ad2, es, ed, N_NODES);
    gat_edge_max<<<EH_BLKS, 256, 0, stream>>>(ei, es, ed, m);
    gat_edge_sum<<<EH_BLKS, 256, 0, stream>>>(ei, es, ed, m, den);
    gat_edge_agg<<<EW_BLKS, 256, 0, stream>>>(ei, es, ed, m, den, T0, T2);
    bias_act<<<GEMM_BLKS, 256, 0, stream>>>(T2, b2, 0);    // H = agg + b2

    // ---------------- node attention ----------------
    node_att<<<NA_BLKS, 256, 0, stream>>>(T2, na_w1, na_b1, na_w2, na_b2, ac, at);

    // ---------------- edge attention ----------------
    gemm_node<64, 64, 0><<<GEMM_BLKS, 256, 0, stream>>>(T2, ea_w1,           T1, nullptr, nullptr, nullptr, nullptr, nullptr, N_NODES); // P1
    gemm_node<64, 64, 0><<<GEMM_BLKS, 256, 0, stream>>>(T2, ea_w1 + 64 * 64, T0, nullptr, nullptr, nullptr, nullptr, nullptr, N_NODES); // P2
    edge_att<<<EA_BLKS, 256, 0, stream>>>(ei, T1, T0, ea_b1, ea_w2, ea_b2, bc, bt);

    // ---------------- GCN degrees ----------------
    hipMemsetAsync(degc, 0, (size_t)2 * N_NODES * 4, stream);
    gcn_deg<<<(E2 + 255) / 256, 256, 0, stream>>>(ei, bc, bt, degc, degt);
    deg_to_dis<<<(N_NODES + 255) / 256, 256, 0, stream>>>(degc, degt);

    hipMemsetAsync(S_c, 0, (size_t)(2 * NG * 64 + NG) * 4, stream);

    // ---------------- branch c ----------------
    gemm_node<64, 64, 2><<<GEMM_BLKS, 256, 0, stream>>>(T2, gc_w, T0, ac, nullptr, nullptr, nullptr, nullptr, N_NODES);
    hipMemsetAsync(T1, 0, nf * 4, stream);
    gcn_agg<<<EW_BLKS, 256, 0, stream>>>(ei, T0, degc, bc, T1);
    readout<<<RO_BLKS, 256, 0, stream>>>(T1, batch, S_c, cntf, 1);

    // ---------------- branch t ----------------
    gemm_node<64, 64, 2><<<GEMM_BLKS, 256, 0, stream>>>(T2, gt_w, T0, at, nullptr, nullptr, nullptr, nullptr, N_NODES);
    hipMemsetAsync(T1, 0, nf * 4, stream);
    gcn_agg<<<EW_BLKS, 256, 0, stream>>>(ei, T0, degt, bt, T1);
    readout<<<RO_BLKS, 256, 0, stream>>>(T1, batch, S_t, cntf, 0);

    // ---------------- heads ----------------
    final_head<<<NG, 64, 0, stream>>>(S_c, S_t, cntf,
                                      gc_b, gt_b, rc_w, rc_b, rt_w, rt_b,
                                      cc_w1, cc_b1, cc_w2, cc_b2,
                                      ct_w1, ct_b1, ct_w2, ct_b2,
                                      cm_w1, cm_b1, cm_w2, cm_b2, out);
    (void)in_sizes; (void)n_in; (void)out_size; (void)ws_size;
}

// Round 2
// 1575.760 us; speedup vs baseline: 1.3862x; 1.3862x over previous
//
#include <hip/hip_runtime.h>
#include <hip/hip_bf16.h>

#define N_NODES 100000
#define E_EDGES 800000
#define E2 (E_EDGES + N_NODES)   // 900000 edges incl. self loops
#define FIN 128
#define HD 64
#define NH 8
#define NG 128
#define NC 10
#define SLOPE 0.2f
#define SELF_FLAG 0x40000000
#define SRC_MASK  0x3FFFFFFF
#define NSCAN_BLK 391            // ceil(N/256)

__device__ __forceinline__ float lrelu(float x) { return x > 0.f ? x : SLOPE * x; }

// ---------------------------------------------------------------------------
// Node GEMM: out[n][j] = sum_k in[n][k] * W[k][j]  (+ epilogues)
// MODE 0: plain.  MODE 1: also es/ed head dots (KOUT must be 64).
// MODE 2: multiply row result by scale[n].
// ---------------------------------------------------------------------------
template<int KIN, int KOUT, int MODE>
__global__ void gemm_node(const float* __restrict__ in, const float* __restrict__ W,
                          float* __restrict__ out, const float* __restrict__ scale,
                          const float* __restrict__ a_s, const float* __restrict__ a_d,
                          float* __restrict__ es, float* __restrict__ ed, int nrows)
{
    __shared__ float Ws[KIN * KOUT];
    for (int i = threadIdx.x; i < KIN * KOUT; i += 256) Ws[i] = W[i];
    __syncthreads();
    int idx = blockIdx.x * 256 + threadIdx.x;
    int n = idx / KOUT;
    int j = idx % KOUT;
    if (n >= nrows) return;
    const float* row = in + (size_t)n * KIN;
    float acc = 0.f;
#pragma unroll 8
    for (int k = 0; k < KIN; ++k) acc = fmaf(row[k], Ws[k * KOUT + j], acc);
    if (MODE == 2) acc *= scale[n];
    out[(size_t)n * KOUT + j] = acc;
    if (MODE == 1) {
        float pes = acc * a_s[j];
        float ped = acc * a_d[j];
#pragma unroll
        for (int o = 1; o < 8; o <<= 1) {
            pes += __shfl_xor(pes, o, 64);
            ped += __shfl_xor(ped, o, 64);
        }
        if ((j & 7) == 0) {
            es[n * NH + (j >> 3)] = pes;
            ed[n * NH + (j >> 3)] = ped;
        }
    }
}

// ---------------------------------------------------------------------------
// CSR build: histogram -> scan -> scatter
// ---------------------------------------------------------------------------
__global__ void csr_hist(const int* __restrict__ ei, int* __restrict__ cnt)
{
    int e = blockIdx.x * 256 + threadIdx.x;
    if (e >= E_EDGES) return;
    atomicAdd(&cnt[ei[E_EDGES + e]], 1);
}

__global__ void csr_scan1(const int* __restrict__ cnt, int* __restrict__ offs,
                          int* __restrict__ bsum)
{
    __shared__ int tmp[256];
    int t = threadIdx.x;
    int i = blockIdx.x * 256 + t;
    int v = (i < N_NODES) ? cnt[i] + 1 : 0;   // +1 = appended self loop
    tmp[t] = v; __syncthreads();
#pragma unroll
    for (int o = 1; o < 256; o <<= 1) {
        int a = (t >= o) ? tmp[t - o] : 0;
        __syncthreads();
        tmp[t] += a;
        __syncthreads();
    }
    if (i < N_NODES) offs[i] = tmp[t] - v;    // block-local exclusive
    if (t == 255) bsum[blockIdx.x] = tmp[255];
}

__global__ void csr_scan2(int* __restrict__ bsum)   // one block, 512 threads
{
    __shared__ int tmp[512];
    int t = threadIdx.x;
    int v = (t < NSCAN_BLK) ? bsum[t] : 0;
    tmp[t] = v; __syncthreads();
#pragma unroll
    for (int o = 1; o < 512; o <<= 1) {
        int a = (t >= o) ? tmp[t - o] : 0;
        __syncthreads();
        tmp[t] += a;
        __syncthreads();
    }
    if (t < NSCAN_BLK) bsum[t] = tmp[t] - v;  // exclusive
}

__global__ void csr_scan3(int* __restrict__ offs, const int* __restrict__ bsum,
                          int* __restrict__ cursor)
{
    int i = blockIdx.x * 256 + threadIdx.x;
    if (i < N_NODES) {
        int v = offs[i] + bsum[blockIdx.x];
        offs[i] = v;
        cursor[i] = v;
    }
    if (i == 0) offs[N_NODES] = E2;
}

__global__ void csr_scatter(const int* __restrict__ ei, int* __restrict__ cursor,
                            int* __restrict__ csr)
{
    int e = blockIdx.x * 256 + threadIdx.x;
    if (e >= E2) return;
    int d, tag;
    if (e < E_EDGES) { int s = ei[e]; d = ei[E_EDGES + e]; tag = s; }
    else             { d = e - E_EDGES; tag = d | SELF_FLAG; }
    int pos = atomicAdd(&cursor[d], 1);
    csr[pos] = tag;
}

// ---------------------------------------------------------------------------
// Fused GAT aggregate: wave per dst node (max, exp-sum, weighted agg, bias, act)
// ---------------------------------------------------------------------------
template<int ELU>
__global__ void gat_aggregate(const int* __restrict__ offs, const int* __restrict__ csr,
                              const float* __restrict__ es, const float* __restrict__ ed,
                              const float* __restrict__ hsrc, const float* __restrict__ bias,
                              float* __restrict__ out)
{
    int n = blockIdx.x * 4 + (threadIdx.x >> 6);
    int lane = threadIdx.x & 63;
    if (n >= N_NODES) return;
    int h = lane >> 3;
    int beg = offs[n], end = offs[n + 1];
    float edv = ed[n * NH + h];
    float mh = -1e30f;
    for (int p = beg; p < end; ++p) {
        int s = csr[p] & SRC_MASK;
        mh = fmaxf(mh, lrelu(es[s * NH + h] + edv));
    }
    float den = 0.f, acc = 0.f;
    for (int p = beg; p < end; ++p) {
        int s = csr[p] & SRC_MASK;
        float l = lrelu(es[s * NH + h] + edv);
        float ex = __expf(l - mh);
        den += ex;
        acc = fmaf(hsrc[(size_t)s * HD + lane], ex, acc);
    }
    float v = acc / (den + 1e-16f) + bias[lane];
    if (ELU) v = v > 0.f ? v : (__expf(v) - 1.f);
    out[(size_t)n * HD + lane] = v;
}

// ---------------------------------------------------------------------------
// node attention -> alpha_c, alpha_t   (wave per node)
// ---------------------------------------------------------------------------
__global__ void node_att(const float* __restrict__ H, const float* __restrict__ w1,
                         const float* __restrict__ b1, const float* __restrict__ w2,
                         const float* __restrict__ b2, float* __restrict__ ac,
                         float* __restrict__ at)
{
    int n = blockIdx.x * 4 + (threadIdx.x >> 6);
    int lane = threadIdx.x & 63;
    if (n >= N_NODES) return;
    const float* row = H + (size_t)n * HD;
    float hid = 0.f;
    if (lane < 32) {
        float a = b1[lane];
#pragma unroll 8
        for (int k = 0; k < HD; ++k) a = fmaf(row[k], w1[k * 32 + lane], a);
        hid = fmaxf(a, 0.f);
    }
    float p0 = lane < 32 ? hid * w2[lane * 2 + 0] : 0.f;
    float p1 = lane < 32 ? hid * w2[lane * 2 + 1] : 0.f;
#pragma unroll
    for (int o = 1; o < 64; o <<= 1) { p0 += __shfl_xor(p0, o, 64); p1 += __shfl_xor(p1, o, 64); }
    if (lane == 0) {
        float z0 = p0 + b2[0], z1 = p1 + b2[1];
        float mx = fmaxf(z0, z1);
        float e0 = __expf(z0 - mx), e1 = __expf(z1 - mx);
        float ssum = e0 + e1;
        ac[n] = e0 / ssum;
        at[n] = e1 / ssum;
    }
}

// ---------------------------------------------------------------------------
// edge attention in CSR order: wave per dst node, loop incoming real edges
// hidden = relu(P1[src] + P2[dst] + b1) -> softmax2 -> bc[pos], bt[pos]
// ---------------------------------------------------------------------------
__global__ void edge_att_node(const int* __restrict__ offs, const int* __restrict__ csr,
                              const float* __restrict__ P1, const float* __restrict__ P2,
                              const float* __restrict__ b1, const float* __restrict__ w2,
                              const float* __restrict__ b2, float* __restrict__ bc,
                              float* __restrict__ bt)
{
    int n = blockIdx.x * 4 + (threadIdx.x >> 6);
    int lane = threadIdx.x & 63;
    if (n >= N_NODES) return;
    float p2v = P2[(size_t)n * HD + lane] + b1[lane];
    float w20 = w2[lane * 2 + 0], w21 = w2[lane * 2 + 1];
    int beg = offs[n], end = offs[n + 1];
    for (int p = beg; p < end; ++p) {
        int sv = csr[p];
        if (sv & SELF_FLAG) continue;
        float hd = fmaxf(P1[(size_t)sv * HD + lane] + p2v, 0.f);
        float p0 = hd * w20;
        float p1 = hd * w21;
#pragma unroll
        for (int o = 1; o < 64; o <<= 1) { p0 += __shfl_xor(p0, o, 64); p1 += __shfl_xor(p1, o, 64); }
        if (lane == 0) {
            float z0 = p0 + b2[0], z1 = p1 + b2[1];
            float mx = fmaxf(z0, z1);
            float e0 = __expf(z0 - mx), e1 = __expf(z1 - mx);
            float ssum = e0 + e1;
            bc[p] = e0 / ssum;
            bt[p] = e1 / ssum;
        }
    }
}

// ---------------------------------------------------------------------------
// GCN: fused degree + rsqrt (thread per node), then gather aggregate (wave/node)
// ---------------------------------------------------------------------------
__global__ void gcn_deg_dis(const int* __restrict__ offs, const int* __restrict__ csr,
                            const float* __restrict__ bc, const float* __restrict__ bt,
                            float* __restrict__ disc, float* __restrict__ dist)
{
    int n = blockIdx.x * 256 + threadIdx.x;
    if (n >= N_NODES) return;
    int beg = offs[n], end = offs[n + 1];
    float dc = 0.f, dt = 0.f;
    for (int p = beg; p < end; ++p) {
        if (csr[p] & SELF_FLAG) { dc += 1.f; dt += 1.f; }
        else { dc += bc[p]; dt += bt[p]; }
    }
    disc[n] = dc > 0.f ? rsqrtf(fmaxf(dc, 1e-20f)) : 0.f;
    dist[n] = dt > 0.f ? rsqrtf(fmaxf(dt, 1e-20f)) : 0.f;
}

__global__ void gcn_aggregate(const int* __restrict__ offs, const int* __restrict__ csr,
                              const float* __restrict__ pre, const float* __restrict__ dis,
                              const float* __restrict__ bw, float* __restrict__ out)
{
    int n = blockIdx.x * 4 + (threadIdx.x >> 6);
    int lane = threadIdx.x & 63;
    if (n >= N_NODES) return;
    float disd = dis[n];
    int beg = offs[n], end = offs[n + 1];
    float acc = 0.f;
    for (int p = beg; p < end; ++p) {
        int sv = csr[p];
        int s = sv & SRC_MASK;
        float w = (sv & SELF_FLAG) ? 1.f : bw[p];
        acc = fmaf(pre[(size_t)s * HD + lane], dis[s] * w * disd, acc);
    }
    out[(size_t)n * HD + lane] = acc;
}

// ---------------------------------------------------------------------------
// readout: segment sum of rows by sorted `batch` -> S[g][64], counts
// ---------------------------------------------------------------------------
__global__ void readout(const float* __restrict__ Gagg, const int* __restrict__ batch,
                        float* __restrict__ S, float* __restrict__ cnt, int do_cnt)
{
    int chunk = blockIdx.x * 4 + (threadIdx.x >> 6);
    int lane = threadIdx.x & 63;
    int n0 = chunk * 128;
    if (n0 >= N_NODES) return;
    int n1 = n0 + 128; if (n1 > N_NODES) n1 = N_NODES;
    int gp = batch[n0];
    float acc = 0.f; int rc = 0;
    for (int n = n0; n < n1; ++n) {
        int g = batch[n];
        if (g != gp) {
            atomicAdd(&S[gp * 64 + lane], acc);
            if (do_cnt && lane == 0) atomicAdd(&cnt[gp], (float)rc);
            acc = 0.f; rc = 0; gp = g;
        }
        acc += Gagg[(size_t)n * 64 + lane];
        ++rc;
    }
    atomicAdd(&S[gp * 64 + lane], acc);
    if (do_cnt && lane == 0) atomicAdd(&cnt[gp], (float)rc);
}

// ---------------------------------------------------------------------------
// final per-graph heads. hGc = (S_c + cnt*gc_b) @ rc_w + cnt*rc_b, etc.
// ---------------------------------------------------------------------------
__global__ void final_head(const float* __restrict__ S_c, const float* __restrict__ S_t,
                           const float* __restrict__ cnt,
                           const float* __restrict__ gc_b, const float* __restrict__ gt_b,
                           const float* __restrict__ rc_w, const float* __restrict__ rc_b,
                           const float* __restrict__ rt_w, const float* __restrict__ rt_b,
                           const float* __restrict__ cc_w1, const float* __restrict__ cc_b1,
                           const float* __restrict__ cc_w2, const float* __restrict__ cc_b2,
                           const float* __restrict__ ct_w1, const float* __restrict__ ct_b1,
                           const float* __restrict__ ct_w2, const float* __restrict__ ct_b2,
                           const float* __restrict__ cm_w1, const float* __restrict__ cm_b1,
                           const float* __restrict__ cm_w2, const float* __restrict__ cm_b2,
                           float* __restrict__ out)
{
    int g = blockIdx.x;
    int j = threadIdx.x;           // 64 threads = 1 wave
    __shared__ float sc[64], st[64], hgc[64], hgt[64], hid[64];
    float c = cnt[g];
    sc[j] = S_c[g * 64 + j] + c * gc_b[j];
    st[j] = S_t[g * 64 + j] + c * gt_b[j];
    __syncthreads();
    float acr = c * rc_b[j], atr = c * rt_b[j];
#pragma unroll 8
    for (int k = 0; k < 64; ++k) {
        acr = fmaf(sc[k], rc_w[k * 64 + j], acr);
        atr = fmaf(st[k], rt_w[k * 64 + j], atr);
    }
    hgc[j] = acr; hgt[j] = atr;
    out[3840 + g * 64 + j]  = acr;   // hGc
    out[12032 + g * 64 + j] = atr;   // hGt
    __syncthreads();
    float hv = 0.f;
    if (j < 32) {
        float a = cc_b1[j];
#pragma unroll 8
        for (int k = 0; k < 64; ++k) a = fmaf(hgc[k], cc_w1[k * 32 + j], a);
        hv = fmaxf(a, 0.f);
    }
    hid[j] = hv;
    __syncthreads();
    if (j < NC) {
        float a = cc_b2[j];
#pragma unroll
        for (int k = 0; k < 32; ++k) a = fmaf(hid[k], cc_w2[k * NC + j], a);
        out[g * NC + j] = a;         // zc
    }
    __syncthreads();
    hv = 0.f;
    if (j < 32) {
        float a = ct_b1[j];
#pragma unroll 8
        for (int k = 0; k < 64; ++k) a = fmaf(hgt[k], ct_w1[k * 32 + j], a);
        hv = fmaxf(a, 0.f);
    }
    hid[j] = hv;
    __syncthreads();
    if (j < NC) {
        float a = ct_b2[j];
#pragma unroll
        for (int k = 0; k < 32; ++k) a = fmaf(hid[k], ct_w2[k * NC + j], a);
        out[1280 + g * NC + j] = a;  // zt
    }
    __syncthreads();
    {
        float a = cm_b1[j];
#pragma unroll 8
        for (int k = 0; k < 64; ++k) {
            a = fmaf(hgc[k], cm_w1[k * 64 + j], a);
            a = fmaf(hgt[k], cm_w1[(64 + k) * 64 + j], a);
        }
        hid[j] = fmaxf(a, 0.f);
    }
    __syncthreads();
    if (j < NC) {
        float a = cm_b2[j];
#pragma unroll 8
        for (int k = 0; k < 64; ++k) a = fmaf(hid[k], cm_w2[k * NC + j], a);
        out[2560 + g * NC + j] = a;  // zp
    }
}

// ---------------------------------------------------------------------------
extern "C" void kernel_launch(void* const* d_in, const int* in_sizes, int n_in,
                              void* d_out, int out_size, void* d_ws, size_t ws_size,
                              hipStream_t stream)
{
    const float* x     = (const float*)d_in[0];
    const int*   ei    = (const int*)d_in[1];
    const int*   batch = (const int*)d_in[2];
    const float* W1    = (const float*)d_in[3];
    const float* as1   = (const float*)d_in[4];
    const float* ad1   = (const float*)d_in[5];
    const float* b1    = (const float*)d_in[6];
    const float* W2    = (const float*)d_in[7];
    const float* as2   = (const float*)d_in[8];
    const float* ad2   = (const float*)d_in[9];
    const float* b2    = (const float*)d_in[10];
    const float* na_w1 = (const float*)d_in[11];
    const float* na_b1 = (const float*)d_in[12];
    const float* na_w2 = (const float*)d_in[13];
    const float* na_b2 = (const float*)d_in[14];
    const float* ea_w1 = (const float*)d_in[15];
    const float* ea_b1 = (const float*)d_in[16];
    const float* ea_w2 = (const float*)d_in[17];
    const float* ea_b2 = (const float*)d_in[18];
    const float* gc_w  = (const float*)d_in[19];
    const float* gc_b  = (const float*)d_in[20];
    const float* gt_w  = (const float*)d_in[21];
    const float* gt_b  = (const float*)d_in[22];
    const float* rc_w  = (const float*)d_in[23];
    const float* rc_b  = (const float*)d_in[24];
    const float* rt_w  = (const float*)d_in[25];
    const float* rt_b  = (const float*)d_in[26];
    const float* cc_w1 = (const float*)d_in[27];
    const float* cc_b1 = (const float*)d_in[28];
    const float* cc_w2 = (const float*)d_in[29];
    const float* cc_b2 = (const float*)d_in[30];
    const float* ct_w1 = (const float*)d_in[31];
    const float* ct_b1 = (const float*)d_in[32];
    const float* ct_w2 = (const float*)d_in[33];
    const float* ct_b2 = (const float*)d_in[34];
    const float* cm_w1 = (const float*)d_in[35];
    const float* cm_b1 = (const float*)d_in[36];
    const float* cm_w2 = (const float*)d_in[37];
    const float* cm_b2 = (const float*)d_in[38];
    float* out = (float*)d_out;

    // workspace layout (floats) — ~96 MB total
    float* ws = (float*)d_ws;
    size_t o = 0;
    const size_t nf = (size_t)N_NODES * HD;
    float* T0   = ws + o; o += nf;
    float* T1   = ws + o; o += nf;
    float* T2   = ws + o; o += nf;             // H (persists)
    float* es   = ws + o; o += (size_t)N_NODES * NH;
    float* ed   = ws + o; o += (size_t)N_NODES * NH;
    float* ac   = ws + o; o += N_NODES;
    float* at   = ws + o; o += N_NODES;
    float* bc   = ws + o; o += E2;             // CSR-ordered edge weights
    float* bt   = ws + o; o += E2;
    float* degc = ws + o; o += N_NODES;        // becomes dis_c
    float* degt = ws + o; o += N_NODES;        // becomes dis_t
    float* S_c  = ws + o; o += NG * 64;        // S_c,S_t,cnt adjacent -> one memset
    float* S_t  = ws + o; o += NG * 64;
    float* cntf = ws + o; o += NG;
    int* csr    = (int*)(ws + o); o += E2;
    int* offs   = (int*)(ws + o); o += N_NODES + 1;
    // CSR-build temporaries alias later-written buffers:
    int* cnt    = (int*)at;     // hist counts (consumed by scan1)
    int* cursor = (int*)ac;     // scatter cursors
    int* bsum   = (int*)degc;   // block sums (391 ints)

    const int GEMM_BLKS = N_NODES * 64 / 256;      // 25000
    const int NW_BLKS   = N_NODES / 4;             // 25000 (wave per node)
    const int NT_BLKS   = (N_NODES + 255) / 256;   // 391
    const int RO_BLKS   = ((N_NODES + 127) / 128 + 3) / 4;  // 196

    // ---------------- CSR build ----------------
    hipMemsetAsync(cnt, 0, (size_t)N_NODES * 4, stream);
    csr_hist<<<(E_EDGES + 255) / 256, 256, 0, stream>>>(ei, cnt);
    csr_scan1<<<NSCAN_BLK, 256, 0, stream>>>(cnt, offs, bsum);
    csr_scan2<<<1, 512, 0, stream>>>(bsum);
    csr_scan3<<<NSCAN_BLK, 256, 0, stream>>>(offs, bsum, cursor);
    csr_scatter<<<(E2 + 255) / 256, 256, 0, stream>>>(ei, cursor, csr);

    // ---------------- GAT layer 1 ----------------
    gemm_node<FIN, 64, 1><<<GEMM_BLKS, 256, 0, stream>>>(x, W1, T0, nullptr, as1, ad1, es, ed, N_NODES);
    gat_aggregate<1><<<NW_BLKS, 256, 0, stream>>>(offs, csr, es, ed, T0, b1, T1);  // H1 = elu(...)

    // ---------------- GAT layer 2 ----------------
    gemm_node<64, 64, 1><<<GEMM_BLKS, 256, 0, stream>>>(T1, W2, T0, nullptr, as2, ad2, es, ed, N_NODES);
    gat_aggregate<0><<<NW_BLKS, 256, 0, stream>>>(offs, csr, es, ed, T0, b2, T2);  // H

    // ---------------- node attention ----------------
    node_att<<<NW_BLKS, 256, 0, stream>>>(T2, na_w1, na_b1, na_w2, na_b2, ac, at);

    // ---------------- edge attention ----------------
    gemm_node<64, 64, 0><<<GEMM_BLKS, 256, 0, stream>>>(T2, ea_w1,           T1, nullptr, nullptr, nullptr, nullptr, nullptr, N_NODES); // P1
    gemm_node<64, 64, 0><<<GEMM_BLKS, 256, 0, stream>>>(T2, ea_w1 + 64 * 64, T0, nullptr, nullptr, nullptr, nullptr, nullptr, N_NODES); // P2
    edge_att_node<<<NW_BLKS, 256, 0, stream>>>(offs, csr, T1, T0, ea_b1, ea_w2, ea_b2, bc, bt);

    // ---------------- GCN norm ----------------
    gcn_deg_dis<<<NT_BLKS, 256, 0, stream>>>(offs, csr, bc, bt, degc, degt);

    hipMemsetAsync(S_c, 0, (size_t)(2 * NG * 64 + NG) * 4, stream);

    // ---------------- branch c ----------------
    gemm_node<64, 64, 2><<<GEMM_BLKS, 256, 0, stream>>>(T2, gc_w, T0, ac, nullptr, nullptr, nullptr, nullptr, N_NODES);
    gcn_aggregate<<<NW_BLKS, 256, 0, stream>>>(offs, csr, T0, degc, bc, T1);
    readout<<<RO_BLKS, 256, 0, stream>>>(T1, batch, S_c, cntf, 1);

    // ---------------- branch t ----------------
    gemm_node<64, 64, 2><<<GEMM_BLKS, 256, 0, stream>>>(T2, gt_w, T0, at, nullptr, nullptr, nullptr, nullptr, N_NODES);
    gcn_aggregate<<<NW_BLKS, 256, 0, stream>>>(offs, csr, T0, degt, bt, T1);
    readout<<<RO_BLKS, 256, 0, stream>>>(T1, batch, S_t, cntf, 0);

    // ---------------- heads ----------------
    final_head<<<NG, 64, 0, stream>>>(S_c, S_t, cntf,
                                      gc_b, gt_b, rc_w, rc_b, rt_w, rt_b,
                                      cc_w1, cc_b1, cc_w2, cc_b2,
                                      ct_w1, ct_b1, ct_w2, ct_b2,
                                      cm_w1, cm_b1, cm_w2, cm_b2, out);
    (void)in_sizes; (void)n_in; (void)out_size; (void)ws_size;
}

// Round 3
// 1184.297 us; speedup vs baseline: 1.8444x; 1.3305x over previous
//
#include <hip/hip_runtime.h>
#include <hip/hip_bf16.h>

#define N_NODES 100000
#define E_EDGES 800000
#define E2 (E_EDGES + N_NODES)   // 900000 edges incl. self loops
#define FIN 128
#define HD 64
#define NH 8
#define NG 128
#define NC 10
#define SLOPE 0.2f
#define SELF_FLAG 0x40000000
#define SRC_MASK  0x3FFFFFFF
#define NSCAN_BLK 391            // ceil(N/256)
#define NBLK64 1563              // ceil(N/64)

__device__ __forceinline__ float lrelu(float x) { return x > 0.f ? x : SLOPE * x; }

// ---------------------------------------------------------------------------
// Tiled node GEMM: 64 nodes/block, thread = 4 nodes x 4 outputs.
// MODE 0: plain. MODE 1: es/ed head-dot epilogue.
// ---------------------------------------------------------------------------
template<int KIN, int MODE>
__global__ __launch_bounds__(256)
void gemm_tile(const float* __restrict__ in, const float* __restrict__ W,
               float* __restrict__ out,
               const float* __restrict__ a_s, const float* __restrict__ a_d,
               float* __restrict__ es, float* __restrict__ ed)
{
    __shared__ float Ws[KIN * 64];
    __shared__ float rows[64 * (KIN + 1)];
    int t = threadIdx.x;
    int base = blockIdx.x * 64;
    {
        const float4* Wv = (const float4*)W;
        float4* Wsv = (float4*)Ws;
        for (int i = t; i < KIN * 16; i += 256) Wsv[i] = Wv[i];
    }
    constexpr int RQ = KIN / 4;
    for (int i = t; i < 64 * RQ; i += 256) {
        int r = i / RQ, c = (i % RQ) * 4;
        int n = base + r;
        float4 v = make_float4(0.f, 0.f, 0.f, 0.f);
        if (n < N_NODES) v = *(const float4*)(in + (size_t)n * KIN + c);
        float* dp = rows + r * (KIN + 1) + c;
        dp[0] = v.x; dp[1] = v.y; dp[2] = v.z; dp[3] = v.w;
    }
    __syncthreads();
    int tr = t >> 4, tc = t & 15;
    float acc[4][4] = {};
    const float4* Wsv = (const float4*)Ws;
#pragma unroll 8
    for (int k = 0; k < KIN; ++k) {
        float4 w = Wsv[k * 16 + tc];
        float rv[4];
#pragma unroll
        for (int i = 0; i < 4; ++i) rv[i] = rows[(tr * 4 + i) * (KIN + 1) + k];
#pragma unroll
        for (int i = 0; i < 4; ++i) {
            acc[i][0] = fmaf(rv[i], w.x, acc[i][0]);
            acc[i][1] = fmaf(rv[i], w.y, acc[i][1]);
            acc[i][2] = fmaf(rv[i], w.z, acc[i][2]);
            acc[i][3] = fmaf(rv[i], w.w, acc[i][3]);
        }
    }
    int j0 = tc * 4;
#pragma unroll
    for (int i = 0; i < 4; ++i) {
        int n = base + tr * 4 + i;
        if (n < N_NODES)
            *(float4*)(out + (size_t)n * 64 + j0) =
                make_float4(acc[i][0], acc[i][1], acc[i][2], acc[i][3]);
    }
    if (MODE == 1) {
        float s0[4], s1[4];
#pragma unroll
        for (int i = 0; i < 4; ++i) {
            float pes = 0.f, ped = 0.f;
#pragma unroll
            for (int q = 0; q < 4; ++q) {
                pes = fmaf(acc[i][q], a_s[j0 + q], pes);
                ped = fmaf(acc[i][q], a_d[j0 + q], ped);
            }
            pes += __shfl_xor(pes, 1, 64);
            ped += __shfl_xor(ped, 1, 64);
            s0[i] = pes; s1[i] = ped;
        }
        if ((tc & 1) == 0) {
            int h = tc >> 1;
#pragma unroll
            for (int i = 0; i < 4; ++i) {
                int n = base + tr * 4 + i;
                if (n < N_NODES) {
                    es[n * NH + h] = s0[i];
                    ed[n * NH + h] = s1[i];
                }
            }
        }
    }
}

// ---------------------------------------------------------------------------
// Dual node GEMM (shared input, two weight mats). SCALED: out_i *= sc_i[n].
// ---------------------------------------------------------------------------
template<int SCALED>
__global__ __launch_bounds__(256)
void gemm_dual(const float* __restrict__ in, const float* __restrict__ W0,
               const float* __restrict__ W1,
               const float* __restrict__ sc0, const float* __restrict__ sc1,
               float* __restrict__ out0, float* __restrict__ out1)
{
    __shared__ float Ws[2 * 64 * 64];
    __shared__ float rows[64 * 65];
    int t = threadIdx.x;
    int base = blockIdx.x * 64;
    {
        const float4* W0v = (const float4*)W0;
        const float4* W1v = (const float4*)W1;
        float4* Wsv = (float4*)Ws;
        for (int i = t; i < 1024; i += 256) { Wsv[i] = W0v[i]; Wsv[1024 + i] = W1v[i]; }
    }
    for (int i = t; i < 64 * 16; i += 256) {
        int r = i / 16, c = (i % 16) * 4;
        int n = base + r;
        float4 v = make_float4(0.f, 0.f, 0.f, 0.f);
        if (n < N_NODES) v = *(const float4*)(in + (size_t)n * 64 + c);
        float* dp = rows + r * 65 + c;
        dp[0] = v.x; dp[1] = v.y; dp[2] = v.z; dp[3] = v.w;
    }
    __syncthreads();
    int tr = t >> 4, tc = t & 15;
    float a0[4][4] = {}, a1[4][4] = {};
    const float4* Wsv = (const float4*)Ws;
#pragma unroll 4
    for (int k = 0; k < 64; ++k) {
        float4 w0 = Wsv[k * 16 + tc];
        float4 w1 = Wsv[1024 + k * 16 + tc];
        float rv[4];
#pragma unroll
        for (int i = 0; i < 4; ++i) rv[i] = rows[(tr * 4 + i) * 65 + k];
#pragma unroll
        for (int i = 0; i < 4; ++i) {
            a0[i][0] = fmaf(rv[i], w0.x, a0[i][0]);
            a0[i][1] = fmaf(rv[i], w0.y, a0[i][1]);
            a0[i][2] = fmaf(rv[i], w0.z, a0[i][2]);
            a0[i][3] = fmaf(rv[i], w0.w, a0[i][3]);
            a1[i][0] = fmaf(rv[i], w1.x, a1[i][0]);
            a1[i][1] = fmaf(rv[i], w1.y, a1[i][1]);
            a1[i][2] = fmaf(rv[i], w1.z, a1[i][2]);
            a1[i][3] = fmaf(rv[i], w1.w, a1[i][3]);
        }
    }
    int j0 = tc * 4;
#pragma unroll
    for (int i = 0; i < 4; ++i) {
        int n = base + tr * 4 + i;
        if (n >= N_NODES) continue;
        float m0 = 1.f, m1 = 1.f;
        if (SCALED) { m0 = sc0[n]; m1 = sc1[n]; }
        *(float4*)(out0 + (size_t)n * 64 + j0) =
            make_float4(a0[i][0] * m0, a0[i][1] * m0, a0[i][2] * m0, a0[i][3] * m0);
        *(float4*)(out1 + (size_t)n * 64 + j0) =
            make_float4(a1[i][0] * m1, a1[i][1] * m1, a1[i][2] * m1, a1[i][3] * m1);
    }
}

// ---------------------------------------------------------------------------
// CSR build: histogram -> scan -> scatter
// ---------------------------------------------------------------------------
__global__ void csr_hist(const int* __restrict__ ei, int* __restrict__ cnt)
{
    int e = blockIdx.x * 256 + threadIdx.x;
    if (e >= E_EDGES) return;
    atomicAdd(&cnt[ei[E_EDGES + e]], 1);
}

__global__ void csr_scan1(const int* __restrict__ cnt, int* __restrict__ offs,
                          int* __restrict__ bsum)
{
    __shared__ int tmp[256];
    int t = threadIdx.x;
    int i = blockIdx.x * 256 + t;
    int v = (i < N_NODES) ? cnt[i] + 1 : 0;
    tmp[t] = v; __syncthreads();
#pragma unroll
    for (int o = 1; o < 256; o <<= 1) {
        int a = (t >= o) ? tmp[t - o] : 0;
        __syncthreads();
        tmp[t] += a;
        __syncthreads();
    }
    if (i < N_NODES) offs[i] = tmp[t] - v;
    if (t == 255) bsum[blockIdx.x] = tmp[255];
}

__global__ void csr_scan2(int* __restrict__ bsum)
{
    __shared__ int tmp[512];
    int t = threadIdx.x;
    int v = (t < NSCAN_BLK) ? bsum[t] : 0;
    tmp[t] = v; __syncthreads();
#pragma unroll
    for (int o = 1; o < 512; o <<= 1) {
        int a = (t >= o) ? tmp[t - o] : 0;
        __syncthreads();
        tmp[t] += a;
        __syncthreads();
    }
    if (t < NSCAN_BLK) bsum[t] = tmp[t] - v;
}

__global__ void csr_scan3(int* __restrict__ offs, const int* __restrict__ bsum,
                          int* __restrict__ cursor)
{
    int i = blockIdx.x * 256 + threadIdx.x;
    if (i < N_NODES) {
        int v = offs[i] + bsum[blockIdx.x];
        offs[i] = v;
        cursor[i] = v;
    }
    if (i == 0) offs[N_NODES] = E2;
}

__global__ void csr_scatter(const int* __restrict__ ei, int* __restrict__ cursor,
                            int* __restrict__ csr)
{
    int e = blockIdx.x * 256 + threadIdx.x;
    if (e >= E2) return;
    int d, tag;
    if (e < E_EDGES) { int s = ei[e]; d = ei[E_EDGES + e]; tag = s; }
    else             { d = e - E_EDGES; tag = d | SELF_FLAG; }
    int pos = atomicAdd(&cursor[d], 1);
    csr[pos] = tag;
}

// ---------------------------------------------------------------------------
// Fused GAT aggregate: wave per dst node
// ---------------------------------------------------------------------------
template<int ELU>
__global__ void gat_aggregate(const int* __restrict__ offs, const int* __restrict__ csr,
                              const float* __restrict__ es, const float* __restrict__ ed,
                              const float* __restrict__ hsrc, const float* __restrict__ bias,
                              float* __restrict__ out)
{
    int n = blockIdx.x * 4 + (threadIdx.x >> 6);
    int lane = threadIdx.x & 63;
    if (n >= N_NODES) return;
    int h = lane >> 3;
    int beg = offs[n], end = offs[n + 1];
    float edv = ed[n * NH + h];
    float mh = -1e30f;
    for (int p = beg; p < end; ++p) {
        int s = csr[p] & SRC_MASK;
        mh = fmaxf(mh, lrelu(es[s * NH + h] + edv));
    }
    float den = 0.f, acc = 0.f;
    for (int p = beg; p < end; ++p) {
        int s = csr[p] & SRC_MASK;
        float l = lrelu(es[s * NH + h] + edv);
        float ex = __expf(l - mh);
        den += ex;
        acc = fmaf(hsrc[(size_t)s * HD + lane], ex, acc);
    }
    float v = acc / (den + 1e-16f) + bias[lane];
    if (ELU) v = v > 0.f ? v : (__expf(v) - 1.f);
    out[(size_t)n * HD + lane] = v;
}

// ---------------------------------------------------------------------------
// node attention -> alpha_c, alpha_t   (wave per node)
// ---------------------------------------------------------------------------
__global__ void node_att(const float* __restrict__ H, const float* __restrict__ w1,
                         const float* __restrict__ b1, const float* __restrict__ w2,
                         const float* __restrict__ b2, float* __restrict__ ac,
                         float* __restrict__ at)
{
    int n = blockIdx.x * 4 + (threadIdx.x >> 6);
    int lane = threadIdx.x & 63;
    if (n >= N_NODES) return;
    const float* row = H + (size_t)n * HD;
    float hid = 0.f;
    if (lane < 32) {
        float a = b1[lane];
#pragma unroll 8
        for (int k = 0; k < HD; ++k) a = fmaf(row[k], w1[k * 32 + lane], a);
        hid = fmaxf(a, 0.f);
    }
    float p0 = lane < 32 ? hid * w2[lane * 2 + 0] : 0.f;
    float p1 = lane < 32 ? hid * w2[lane * 2 + 1] : 0.f;
#pragma unroll
    for (int o = 1; o < 64; o <<= 1) { p0 += __shfl_xor(p0, o, 64); p1 += __shfl_xor(p1, o, 64); }
    if (lane == 0) {
        float z0 = p0 + b2[0], z1 = p1 + b2[1];
        float mx = fmaxf(z0, z1);
        float e0 = __expf(z0 - mx), e1 = __expf(z1 - mx);
        float ssum = e0 + e1;
        ac[n] = e0 / ssum;
        at[n] = e1 / ssum;
    }
}

// ---------------------------------------------------------------------------
// edge attention in CSR order: wave per dst node
// ---------------------------------------------------------------------------
__global__ void edge_att_node(const int* __restrict__ offs, const int* __restrict__ csr,
                              const float* __restrict__ P1, const float* __restrict__ P2,
                              const float* __restrict__ b1, const float* __restrict__ w2,
                              const float* __restrict__ b2, float* __restrict__ bc,
                              float* __restrict__ bt)
{
    int n = blockIdx.x * 4 + (threadIdx.x >> 6);
    int lane = threadIdx.x & 63;
    if (n >= N_NODES) return;
    float p2v = P2[(size_t)n * HD + lane] + b1[lane];
    float w20 = w2[lane * 2 + 0], w21 = w2[lane * 2 + 1];
    int beg = offs[n], end = offs[n + 1];
    for (int p = beg; p < end; ++p) {
        int sv = csr[p];
        if (sv & SELF_FLAG) continue;
        float hd = fmaxf(P1[(size_t)sv * HD + lane] + p2v, 0.f);
        float p0 = hd * w20;
        float p1 = hd * w21;
#pragma unroll
        for (int o = 1; o < 64; o <<= 1) { p0 += __shfl_xor(p0, o, 64); p1 += __shfl_xor(p1, o, 64); }
        if (lane == 0) {
            float z0 = p0 + b2[0], z1 = p1 + b2[1];
            float mx = fmaxf(z0, z1);
            float e0 = __expf(z0 - mx), e1 = __expf(z1 - mx);
            float ssum = e0 + e1;
            bc[p] = e0 / ssum;
            bt[p] = e1 / ssum;
        }
    }
}

// ---------------------------------------------------------------------------
// GCN: fused degree + rsqrt, then gather aggregate
// ---------------------------------------------------------------------------
__global__ void gcn_deg_dis(const int* __restrict__ offs, const int* __restrict__ csr,
                            const float* __restrict__ bc, const float* __restrict__ bt,
                            float* __restrict__ disc, float* __restrict__ dist)
{
    int n = blockIdx.x * 256 + threadIdx.x;
    if (n >= N_NODES) return;
    int beg = offs[n], end = offs[n + 1];
    float dc = 0.f, dt = 0.f;
    for (int p = beg; p < end; ++p) {
        if (csr[p] & SELF_FLAG) { dc += 1.f; dt += 1.f; }
        else { dc += bc[p]; dt += bt[p]; }
    }
    disc[n] = dc > 0.f ? rsqrtf(fmaxf(dc, 1e-20f)) : 0.f;
    dist[n] = dt > 0.f ? rsqrtf(fmaxf(dt, 1e-20f)) : 0.f;
}

__global__ void gcn_aggregate(const int* __restrict__ offs, const int* __restrict__ csr,
                              const float* __restrict__ pre, const float* __restrict__ dis,
                              const float* __restrict__ bw, float* __restrict__ out)
{
    int n = blockIdx.x * 4 + (threadIdx.x >> 6);
    int lane = threadIdx.x & 63;
    if (n >= N_NODES) return;
    float disd = dis[n];
    int beg = offs[n], end = offs[n + 1];
    float acc = 0.f;
    for (int p = beg; p < end; ++p) {
        int sv = csr[p];
        int s = sv & SRC_MASK;
        float w = (sv & SELF_FLAG) ? 1.f : bw[p];
        acc = fmaf(pre[(size_t)s * HD + lane], dis[s] * w * disd, acc);
    }
    out[(size_t)n * HD + lane] = acc;
}

// ---------------------------------------------------------------------------
// readout: segment sum of rows by sorted `batch`
// ---------------------------------------------------------------------------
__global__ void readout(const float* __restrict__ Gagg, const int* __restrict__ batch,
                        float* __restrict__ S, float* __restrict__ cnt, int do_cnt)
{
    int chunk = blockIdx.x * 4 + (threadIdx.x >> 6);
    int lane = threadIdx.x & 63;
    int n0 = chunk * 128;
    if (n0 >= N_NODES) return;
    int n1 = n0 + 128; if (n1 > N_NODES) n1 = N_NODES;
    int gp = batch[n0];
    float acc = 0.f; int rc = 0;
    for (int n = n0; n < n1; ++n) {
        int g = batch[n];
        if (g != gp) {
            atomicAdd(&S[gp * 64 + lane], acc);
            if (do_cnt && lane == 0) atomicAdd(&cnt[gp], (float)rc);
            acc = 0.f; rc = 0; gp = g;
        }
        acc += Gagg[(size_t)n * 64 + lane];
        ++rc;
    }
    atomicAdd(&S[gp * 64 + lane], acc);
    if (do_cnt && lane == 0) atomicAdd(&cnt[gp], (float)rc);
}

// ---------------------------------------------------------------------------
// final per-graph heads
// ---------------------------------------------------------------------------
__global__ void final_head(const float* __restrict__ S_c, const float* __restrict__ S_t,
                           const float* __restrict__ cnt,
                           const float* __restrict__ gc_b, const float* __restrict__ gt_b,
                           const float* __restrict__ rc_w, const float* __restrict__ rc_b,
                           const float* __restrict__ rt_w, const float* __restrict__ rt_b,
                           const float* __restrict__ cc_w1, const float* __restrict__ cc_b1,
                           const float* __restrict__ cc_w2, const float* __restrict__ cc_b2,
                           const float* __restrict__ ct_w1, const float* __restrict__ ct_b1,
                           const float* __restrict__ ct_w2, const float* __restrict__ ct_b2,
                           const float* __restrict__ cm_w1, const float* __restrict__ cm_b1,
                           const float* __restrict__ cm_w2, const float* __restrict__ cm_b2,
                           float* __restrict__ out)
{
    int g = blockIdx.x;
    int j = threadIdx.x;
    __shared__ float sc[64], st[64], hgc[64], hgt[64], hid[64];
    float c = cnt[g];
    sc[j] = S_c[g * 64 + j] + c * gc_b[j];
    st[j] = S_t[g * 64 + j] + c * gt_b[j];
    __syncthreads();
    float acr = c * rc_b[j], atr = c * rt_b[j];
#pragma unroll 8
    for (int k = 0; k < 64; ++k) {
        acr = fmaf(sc[k], rc_w[k * 64 + j], acr);
        atr = fmaf(st[k], rt_w[k * 64 + j], atr);
    }
    hgc[j] = acr; hgt[j] = atr;
    out[3840 + g * 64 + j]  = acr;
    out[12032 + g * 64 + j] = atr;
    __syncthreads();
    float hv = 0.f;
    if (j < 32) {
        float a = cc_b1[j];
#pragma unroll 8
        for (int k = 0; k < 64; ++k) a = fmaf(hgc[k], cc_w1[k * 32 + j], a);
        hv = fmaxf(a, 0.f);
    }
    hid[j] = hv;
    __syncthreads();
    if (j < NC) {
        float a = cc_b2[j];
#pragma unroll
        for (int k = 0; k < 32; ++k) a = fmaf(hid[k], cc_w2[k * NC + j], a);
        out[g * NC + j] = a;
    }
    __syncthreads();
    hv = 0.f;
    if (j < 32) {
        float a = ct_b1[j];
#pragma unroll 8
        for (int k = 0; k < 64; ++k) a = fmaf(hgt[k], ct_w1[k * 32 + j], a);
        hv = fmaxf(a, 0.f);
    }
    hid[j] = hv;
    __syncthreads();
    if (j < NC) {
        float a = ct_b2[j];
#pragma unroll
        for (int k = 0; k < 32; ++k) a = fmaf(hid[k], ct_w2[k * NC + j], a);
        out[1280 + g * NC + j] = a;
    }
    __syncthreads();
    {
        float a = cm_b1[j];
#pragma unroll 8
        for (int k = 0; k < 64; ++k) {
            a = fmaf(hgc[k], cm_w1[k * 64 + j], a);
            a = fmaf(hgt[k], cm_w1[(64 + k) * 64 + j], a);
        }
        hid[j] = fmaxf(a, 0.f);
    }
    __syncthreads();
    if (j < NC) {
        float a = cm_b2[j];
#pragma unroll 8
        for (int k = 0; k < 64; ++k) a = fmaf(hid[k], cm_w2[k * NC + j], a);
        out[2560 + g * NC + j] = a;
    }
}

// ---------------------------------------------------------------------------
extern "C" void kernel_launch(void* const* d_in, const int* in_sizes, int n_in,
                              void* d_out, int out_size, void* d_ws, size_t ws_size,
                              hipStream_t stream)
{
    const float* x     = (const float*)d_in[0];
    const int*   ei    = (const int*)d_in[1];
    const int*   batch = (const int*)d_in[2];
    const float* W1    = (const float*)d_in[3];
    const float* as1   = (const float*)d_in[4];
    const float* ad1   = (const float*)d_in[5];
    const float* b1    = (const float*)d_in[6];
    const float* W2    = (const float*)d_in[7];
    const float* as2   = (const float*)d_in[8];
    const float* ad2   = (const float*)d_in[9];
    const float* b2    = (const float*)d_in[10];
    const float* na_w1 = (const float*)d_in[11];
    const float* na_b1 = (const float*)d_in[12];
    const float* na_w2 = (const float*)d_in[13];
    const float* na_b2 = (const float*)d_in[14];
    const float* ea_w1 = (const float*)d_in[15];
    const float* ea_b1 = (const float*)d_in[16];
    const float* ea_w2 = (const float*)d_in[17];
    const float* ea_b2 = (const float*)d_in[18];
    const float* gc_w  = (const float*)d_in[19];
    const float* gc_b  = (const float*)d_in[20];
    const float* gt_w  = (const float*)d_in[21];
    const float* gt_b  = (const float*)d_in[22];
    const float* rc_w  = (const float*)d_in[23];
    const float* rc_b  = (const float*)d_in[24];
    const float* rt_w  = (const float*)d_in[25];
    const float* rt_b  = (const float*)d_in[26];
    const float* cc_w1 = (const float*)d_in[27];
    const float* cc_b1 = (const float*)d_in[28];
    const float* cc_w2 = (const float*)d_in[29];
    const float* cc_b2 = (const float*)d_in[30];
    const float* ct_w1 = (const float*)d_in[31];
    const float* ct_b1 = (const float*)d_in[32];
    const float* ct_w2 = (const float*)d_in[33];
    const float* ct_b2 = (const float*)d_in[34];
    const float* cm_w1 = (const float*)d_in[35];
    const float* cm_b1 = (const float*)d_in[36];
    const float* cm_w2 = (const float*)d_in[37];
    const float* cm_b2 = (const float*)d_in[38];
    float* out = (float*)d_out;

    float* ws = (float*)d_ws;
    size_t o = 0;
    const size_t nf = (size_t)N_NODES * HD;
    float* T0   = ws + o; o += nf;
    float* T1   = ws + o; o += nf;
    float* T2   = ws + o; o += nf;             // H / later reused as agg buffer
    float* es   = ws + o; o += (size_t)N_NODES * NH;
    float* ed   = ws + o; o += (size_t)N_NODES * NH;
    float* ac   = ws + o; o += N_NODES;
    float* at   = ws + o; o += N_NODES;
    float* bc   = ws + o; o += E2;
    float* bt   = ws + o; o += E2;
    float* degc = ws + o; o += N_NODES;
    float* degt = ws + o; o += N_NODES;
    float* S_c  = ws + o; o += NG * 64;
    float* S_t  = ws + o; o += NG * 64;
    float* cntf = ws + o; o += NG;
    int* csr    = (int*)(ws + o); o += E2;
    int* offs   = (int*)(ws + o); o += N_NODES + 1;
    int* cnt    = (int*)at;
    int* cursor = (int*)ac;
    int* bsum   = (int*)degc;

    const int NW_BLKS = N_NODES / 4;             // 25000
    const int NT_BLKS = (N_NODES + 255) / 256;   // 391
    const int RO_BLKS = ((N_NODES + 127) / 128 + 3) / 4;  // 196

    // ---------------- CSR build ----------------
    hipMemsetAsync(cnt, 0, (size_t)N_NODES * 4, stream);
    csr_hist<<<(E_EDGES + 255) / 256, 256, 0, stream>>>(ei, cnt);
    csr_scan1<<<NSCAN_BLK, 256, 0, stream>>>(cnt, offs, bsum);
    csr_scan2<<<1, 512, 0, stream>>>(bsum);
    csr_scan3<<<NSCAN_BLK, 256, 0, stream>>>(offs, bsum, cursor);
    csr_scatter<<<(E2 + 255) / 256, 256, 0, stream>>>(ei, cursor, csr);

    // ---------------- GAT layer 1 ----------------
    gemm_tile<FIN, 1><<<NBLK64, 256, 0, stream>>>(x, W1, T0, as1, ad1, es, ed);
    gat_aggregate<1><<<NW_BLKS, 256, 0, stream>>>(offs, csr, es, ed, T0, b1, T1);

    // ---------------- GAT layer 2 ----------------
    gemm_tile<64, 1><<<NBLK64, 256, 0, stream>>>(T1, W2, T0, as2, ad2, es, ed);
    gat_aggregate<0><<<NW_BLKS, 256, 0, stream>>>(offs, csr, es, ed, T0, b2, T2);

    // ---------------- node attention ----------------
    node_att<<<NW_BLKS, 256, 0, stream>>>(T2, na_w1, na_b1, na_w2, na_b2, ac, at);

    // ---------------- edge attention (P1 -> T1, P2 -> T0) ----------------
    gemm_dual<0><<<NBLK64, 256, 0, stream>>>(T2, ea_w1, ea_w1 + 64 * 64,
                                             nullptr, nullptr, T1, T0);
    edge_att_node<<<NW_BLKS, 256, 0, stream>>>(offs, csr, T1, T0, ea_b1, ea_w2, ea_b2, bc, bt);

    // ---------------- GCN norm ----------------
    gcn_deg_dis<<<NT_BLKS, 256, 0, stream>>>(offs, csr, bc, bt, degc, degt);

    hipMemsetAsync(S_c, 0, (size_t)(2 * NG * 64 + NG) * 4, stream);

    // ---------------- GCN pre-transforms (Hc_pre -> T0, Ht_pre -> T1) -------
    gemm_dual<1><<<NBLK64, 256, 0, stream>>>(T2, gc_w, gt_w, ac, at, T0, T1);

    // ---------------- branch c ----------------
    gcn_aggregate<<<NW_BLKS, 256, 0, stream>>>(offs, csr, T0, degc, bc, T2);
    readout<<<RO_BLKS, 256, 0, stream>>>(T2, batch, S_c, cntf, 1);

    // ---------------- branch t ----------------
    gcn_aggregate<<<NW_BLKS, 256, 0, stream>>>(offs, csr, T1, degt, bt, T2);
    readout<<<RO_BLKS, 256, 0, stream>>>(T2, batch, S_t, cntf, 0);

    // ---------------- heads ----------------
    final_head<<<NG, 64, 0, stream>>>(S_c, S_t, cntf,
                                      gc_b, gt_b, rc_w, rc_b, rt_w, rt_b,
                                      cc_w1, cc_b1, cc_w2, cc_b2,
                                      ct_w1, ct_b1, ct_w2, ct_b2,
                                      cm_w1, cm_b1, cm_w2, cm_b2, out);
    (void)in_sizes; (void)n_in; (void)out_size; (void)ws_size;
}

// Round 4
// 948.219 us; speedup vs baseline: 2.3036x; 1.2490x over previous
//
#include <hip/hip_runtime.h>
#include <hip/hip_bf16.h>

#define N_NODES 100000
#define E_EDGES 800000
#define E2 (E_EDGES + N_NODES)   // 900000 edges incl. self loops
#define FIN 128
#define HD 64
#define NH 8
#define NG 128
#define NC 10
#define SLOPE 0.2f
#define SELF_FLAG 0x40000000
#define SRC_MASK  0x3FFFFFFF
#define NSCAN_BLK 391            // ceil(N/256)
#define NBLK64 1563              // ceil(N/64)

__device__ __forceinline__ float lrelu(float x) { return x > 0.f ? x : SLOPE * x; }

// ---------------------------------------------------------------------------
// Tiled node GEMM: 64 nodes/block, thread = 4 nodes x 4 outputs.
// MODE 0: plain. MODE 1: es/ed head-dot epilogue.
// ---------------------------------------------------------------------------
template<int KIN, int MODE>
__global__ __launch_bounds__(256)
void gemm_tile(const float* __restrict__ in, const float* __restrict__ W,
               float* __restrict__ out,
               const float* __restrict__ a_s, const float* __restrict__ a_d,
               float* __restrict__ es, float* __restrict__ ed)
{
    __shared__ float Ws[KIN * 64];
    __shared__ float rows[64 * (KIN + 1)];
    int t = threadIdx.x;
    int base = blockIdx.x * 64;
    {
        const float4* Wv = (const float4*)W;
        float4* Wsv = (float4*)Ws;
        for (int i = t; i < KIN * 16; i += 256) Wsv[i] = Wv[i];
    }
    constexpr int RQ = KIN / 4;
    for (int i = t; i < 64 * RQ; i += 256) {
        int r = i / RQ, c = (i % RQ) * 4;
        int n = base + r;
        float4 v = make_float4(0.f, 0.f, 0.f, 0.f);
        if (n < N_NODES) v = *(const float4*)(in + (size_t)n * KIN + c);
        float* dp = rows + r * (KIN + 1) + c;
        dp[0] = v.x; dp[1] = v.y; dp[2] = v.z; dp[3] = v.w;
    }
    __syncthreads();
    int tr = t >> 4, tc = t & 15;
    float acc[4][4] = {};
    const float4* Wsv = (const float4*)Ws;
#pragma unroll 8
    for (int k = 0; k < KIN; ++k) {
        float4 w = Wsv[k * 16 + tc];
        float rv[4];
#pragma unroll
        for (int i = 0; i < 4; ++i) rv[i] = rows[(tr * 4 + i) * (KIN + 1) + k];
#pragma unroll
        for (int i = 0; i < 4; ++i) {
            acc[i][0] = fmaf(rv[i], w.x, acc[i][0]);
            acc[i][1] = fmaf(rv[i], w.y, acc[i][1]);
            acc[i][2] = fmaf(rv[i], w.z, acc[i][2]);
            acc[i][3] = fmaf(rv[i], w.w, acc[i][3]);
        }
    }
    int j0 = tc * 4;
#pragma unroll
    for (int i = 0; i < 4; ++i) {
        int n = base + tr * 4 + i;
        if (n < N_NODES)
            *(float4*)(out + (size_t)n * 64 + j0) =
                make_float4(acc[i][0], acc[i][1], acc[i][2], acc[i][3]);
    }
    if (MODE == 1) {
        float s0[4], s1[4];
#pragma unroll
        for (int i = 0; i < 4; ++i) {
            float pes = 0.f, ped = 0.f;
#pragma unroll
            for (int q = 0; q < 4; ++q) {
                pes = fmaf(acc[i][q], a_s[j0 + q], pes);
                ped = fmaf(acc[i][q], a_d[j0 + q], ped);
            }
            pes += __shfl_xor(pes, 1, 64);
            ped += __shfl_xor(ped, 1, 64);
            s0[i] = pes; s1[i] = ped;
        }
        if ((tc & 1) == 0) {
            int h = tc >> 1;
#pragma unroll
            for (int i = 0; i < 4; ++i) {
                int n = base + tr * 4 + i;
                if (n < N_NODES) {
                    es[n * NH + h] = s0[i];
                    ed[n * NH + h] = s1[i];
                }
            }
        }
    }
}

// ---------------------------------------------------------------------------
// Dual node GEMM (shared input, two weight mats). SCALED: out_i *= sc_i[n].
// ---------------------------------------------------------------------------
template<int SCALED>
__global__ __launch_bounds__(256)
void gemm_dual(const float* __restrict__ in, const float* __restrict__ W0,
               const float* __restrict__ W1,
               const float* __restrict__ sc0, const float* __restrict__ sc1,
               float* __restrict__ out0, float* __restrict__ out1)
{
    __shared__ float Ws[2 * 64 * 64];
    __shared__ float rows[64 * 65];
    int t = threadIdx.x;
    int base = blockIdx.x * 64;
    {
        const float4* W0v = (const float4*)W0;
        const float4* W1v = (const float4*)W1;
        float4* Wsv = (float4*)Ws;
        for (int i = t; i < 1024; i += 256) { Wsv[i] = W0v[i]; Wsv[1024 + i] = W1v[i]; }
    }
    for (int i = t; i < 64 * 16; i += 256) {
        int r = i / 16, c = (i % 16) * 4;
        int n = base + r;
        float4 v = make_float4(0.f, 0.f, 0.f, 0.f);
        if (n < N_NODES) v = *(const float4*)(in + (size_t)n * 64 + c);
        float* dp = rows + r * 65 + c;
        dp[0] = v.x; dp[1] = v.y; dp[2] = v.z; dp[3] = v.w;
    }
    __syncthreads();
    int tr = t >> 4, tc = t & 15;
    float a0[4][4] = {}, a1[4][4] = {};
    const float4* Wsv = (const float4*)Ws;
#pragma unroll 4
    for (int k = 0; k < 64; ++k) {
        float4 w0 = Wsv[k * 16 + tc];
        float4 w1 = Wsv[1024 + k * 16 + tc];
        float rv[4];
#pragma unroll
        for (int i = 0; i < 4; ++i) rv[i] = rows[(tr * 4 + i) * 65 + k];
#pragma unroll
        for (int i = 0; i < 4; ++i) {
            a0[i][0] = fmaf(rv[i], w0.x, a0[i][0]);
            a0[i][1] = fmaf(rv[i], w0.y, a0[i][1]);
            a0[i][2] = fmaf(rv[i], w0.z, a0[i][2]);
            a0[i][3] = fmaf(rv[i], w0.w, a0[i][3]);
            a1[i][0] = fmaf(rv[i], w1.x, a1[i][0]);
            a1[i][1] = fmaf(rv[i], w1.y, a1[i][1]);
            a1[i][2] = fmaf(rv[i], w1.z, a1[i][2]);
            a1[i][3] = fmaf(rv[i], w1.w, a1[i][3]);
        }
    }
    int j0 = tc * 4;
#pragma unroll
    for (int i = 0; i < 4; ++i) {
        int n = base + tr * 4 + i;
        if (n >= N_NODES) continue;
        float m0 = 1.f, m1 = 1.f;
        if (SCALED) { m0 = sc0[n]; m1 = sc1[n]; }
        *(float4*)(out0 + (size_t)n * 64 + j0) =
            make_float4(a0[i][0] * m0, a0[i][1] * m0, a0[i][2] * m0, a0[i][3] * m0);
        *(float4*)(out1 + (size_t)n * 64 + j0) =
            make_float4(a1[i][0] * m1, a1[i][1] * m1, a1[i][2] * m1, a1[i][3] * m1);
    }
}

// ---------------------------------------------------------------------------
// CSR build: histogram -> scan -> scatter (+ dst array)
// ---------------------------------------------------------------------------
__global__ void csr_hist(const int* __restrict__ ei, int* __restrict__ cnt)
{
    int e = blockIdx.x * 256 + threadIdx.x;
    if (e >= E_EDGES) return;
    atomicAdd(&cnt[ei[E_EDGES + e]], 1);
}

__global__ void csr_scan1(const int* __restrict__ cnt, int* __restrict__ offs,
                          int* __restrict__ bsum)
{
    __shared__ int tmp[256];
    int t = threadIdx.x;
    int i = blockIdx.x * 256 + t;
    int v = (i < N_NODES) ? cnt[i] + 1 : 0;
    tmp[t] = v; __syncthreads();
#pragma unroll
    for (int o = 1; o < 256; o <<= 1) {
        int a = (t >= o) ? tmp[t - o] : 0;
        __syncthreads();
        tmp[t] += a;
        __syncthreads();
    }
    if (i < N_NODES) offs[i] = tmp[t] - v;
    if (t == 255) bsum[blockIdx.x] = tmp[255];
}

__global__ void csr_scan2(int* __restrict__ bsum)
{
    __shared__ int tmp[512];
    int t = threadIdx.x;
    int v = (t < NSCAN_BLK) ? bsum[t] : 0;
    tmp[t] = v; __syncthreads();
#pragma unroll
    for (int o = 1; o < 512; o <<= 1) {
        int a = (t >= o) ? tmp[t - o] : 0;
        __syncthreads();
        tmp[t] += a;
        __syncthreads();
    }
    if (t < NSCAN_BLK) bsum[t] = tmp[t] - v;
}

__global__ void csr_scan3(int* __restrict__ offs, const int* __restrict__ bsum,
                          int* __restrict__ cursor)
{
    int i = blockIdx.x * 256 + threadIdx.x;
    if (i < N_NODES) {
        int v = offs[i] + bsum[blockIdx.x];
        offs[i] = v;
        cursor[i] = v;
    }
    if (i == 0) offs[N_NODES] = E2;
}

__global__ void csr_scatter(const int* __restrict__ ei, int* __restrict__ cursor,
                            int* __restrict__ csr, int* __restrict__ csrd)
{
    int e = blockIdx.x * 256 + threadIdx.x;
    if (e >= E2) return;
    int d, tag;
    if (e < E_EDGES) { int s = ei[e]; d = ei[E_EDGES + e]; tag = s; }
    else             { d = e - E_EDGES; tag = d | SELF_FLAG; }
    int pos = atomicAdd(&cursor[d], 1);
    csr[pos] = tag;
    csrd[pos] = d;
}

// ---------------------------------------------------------------------------
// Fused GAT aggregate: wave per dst node, 2x unrolled gather loop
// ---------------------------------------------------------------------------
template<int ELU>
__global__ void gat_aggregate(const int* __restrict__ offs, const int* __restrict__ csr,
                              const float* __restrict__ es, const float* __restrict__ ed,
                              const float* __restrict__ hsrc, const float* __restrict__ bias,
                              float* __restrict__ out)
{
    int n = blockIdx.x * 4 + (threadIdx.x >> 6);
    int lane = threadIdx.x & 63;
    if (n >= N_NODES) return;
    int h = lane >> 3;
    int beg = offs[n], end = offs[n + 1];
    float edv = ed[n * NH + h];
    float mh = -1e30f;
    {
        int p = beg;
        for (; p + 2 <= end; p += 2) {
            int s0 = csr[p] & SRC_MASK, s1 = csr[p + 1] & SRC_MASK;
            float l0 = lrelu(es[s0 * NH + h] + edv);
            float l1 = lrelu(es[s1 * NH + h] + edv);
            mh = fmaxf(mh, fmaxf(l0, l1));
        }
        if (p < end) {
            int s0 = csr[p] & SRC_MASK;
            mh = fmaxf(mh, lrelu(es[s0 * NH + h] + edv));
        }
    }
    float den = 0.f, acc = 0.f;
    {
        int p = beg;
        for (; p + 2 <= end; p += 2) {
            int s0 = csr[p] & SRC_MASK, s1 = csr[p + 1] & SRC_MASK;
            float r0 = hsrc[(size_t)s0 * HD + lane];
            float r1 = hsrc[(size_t)s1 * HD + lane];
            float l0 = lrelu(es[s0 * NH + h] + edv);
            float l1 = lrelu(es[s1 * NH + h] + edv);
            float e0 = __expf(l0 - mh), e1 = __expf(l1 - mh);
            den += e0 + e1;
            acc = fmaf(r0, e0, acc);
            acc = fmaf(r1, e1, acc);
        }
        if (p < end) {
            int s0 = csr[p] & SRC_MASK;
            float l0 = lrelu(es[s0 * NH + h] + edv);
            float e0 = __expf(l0 - mh);
            den += e0;
            acc = fmaf(hsrc[(size_t)s0 * HD + lane], e0, acc);
        }
    }
    float v = acc / (den + 1e-16f) + bias[lane];
    if (ELU) v = v > 0.f ? v : (__expf(v) - 1.f);
    out[(size_t)n * HD + lane] = v;
}

// ---------------------------------------------------------------------------
// node attention -> alpha_c, alpha_t   (wave per node)
// ---------------------------------------------------------------------------
__global__ void node_att(const float* __restrict__ H, const float* __restrict__ w1,
                         const float* __restrict__ b1, const float* __restrict__ w2,
                         const float* __restrict__ b2, float* __restrict__ ac,
                         float* __restrict__ at)
{
    int n = blockIdx.x * 4 + (threadIdx.x >> 6);
    int lane = threadIdx.x & 63;
    if (n >= N_NODES) return;
    const float* row = H + (size_t)n * HD;
    float hid = 0.f;
    if (lane < 32) {
        float a = b1[lane];
#pragma unroll 8
        for (int k = 0; k < HD; ++k) a = fmaf(row[k], w1[k * 32 + lane], a);
        hid = fmaxf(a, 0.f);
    }
    float p0 = lane < 32 ? hid * w2[lane * 2 + 0] : 0.f;
    float p1 = lane < 32 ? hid * w2[lane * 2 + 1] : 0.f;
#pragma unroll
    for (int o = 1; o < 64; o <<= 1) { p0 += __shfl_xor(p0, o, 64); p1 += __shfl_xor(p1, o, 64); }
    if (lane == 0) {
        float z0 = p0 + b2[0], z1 = p1 + b2[1];
        float mx = fmaxf(z0, z1);
        float e0 = __expf(z0 - mx), e1 = __expf(z1 - mx);
        float ssum = e0 + e1;
        ac[n] = e0 / ssum;
        at[n] = e1 / ssum;
    }
}

// ---------------------------------------------------------------------------
// edge attention, flat over CSR positions: 8 lanes per edge, 8 edges per wave
// ---------------------------------------------------------------------------
__global__ __launch_bounds__(256)
void edge_att_flat(const int* __restrict__ csr, const int* __restrict__ csrd,
                   const float* __restrict__ P1, const float* __restrict__ P2,
                   const float* __restrict__ b1, const float* __restrict__ w2,
                   const float* __restrict__ b2,
                   float* __restrict__ bc, float* __restrict__ bt)
{
    int lane = threadIdx.x & 63;
    int sg = lane >> 3, q = lane & 7;
    int p = (blockIdx.x * 4 + (threadIdx.x >> 6)) * 8 + sg;
    if (p >= E2) return;
    int sv = csr[p];
    if (sv & SELF_FLAG) return;
    int d = csrd[p];
    const float4* pu = (const float4*)(P1 + (size_t)sv * 64 + q * 8);
    const float4* pv = (const float4*)(P2 + (size_t)d * 64 + q * 8);
    const float4* pb = (const float4*)(b1 + q * 8);
    const float4* pw = (const float4*)(w2 + q * 16);
    float4 u0 = pu[0], u1 = pu[1];
    float4 v0 = pv[0], v1 = pv[1];
    float4 c0 = pb[0], c1 = pb[1];
    float4 w0 = pw[0], w1v = pw[1], w2v = pw[2], w3v = pw[3];
    float h0 = fmaxf(u0.x + v0.x + c0.x, 0.f);
    float h1 = fmaxf(u0.y + v0.y + c0.y, 0.f);
    float h2 = fmaxf(u0.z + v0.z + c0.z, 0.f);
    float h3 = fmaxf(u0.w + v0.w + c0.w, 0.f);
    float h4 = fmaxf(u1.x + v1.x + c1.x, 0.f);
    float h5 = fmaxf(u1.y + v1.y + c1.y, 0.f);
    float h6 = fmaxf(u1.z + v1.z + c1.z, 0.f);
    float h7 = fmaxf(u1.w + v1.w + c1.w, 0.f);
    float z0 = h0 * w0.x + h1 * w0.z + h2 * w1v.x + h3 * w1v.z
             + h4 * w2v.x + h5 * w2v.z + h6 * w3v.x + h7 * w3v.z;
    float z1 = h0 * w0.y + h1 * w0.w + h2 * w1v.y + h3 * w1v.w
             + h4 * w2v.y + h5 * w2v.w + h6 * w3v.y + h7 * w3v.w;
    z0 += __shfl_xor(z0, 1, 64); z1 += __shfl_xor(z1, 1, 64);
    z0 += __shfl_xor(z0, 2, 64); z1 += __shfl_xor(z1, 2, 64);
    z0 += __shfl_xor(z0, 4, 64); z1 += __shfl_xor(z1, 4, 64);
    if (q == 0) {
        z0 += b2[0]; z1 += b2[1];
        float mx = fmaxf(z0, z1);
        float e0 = __expf(z0 - mx), e1 = __expf(z1 - mx);
        float ss = e0 + e1;
        bc[p] = e0 / ss;
        bt[p] = e1 / ss;
    }
}

// ---------------------------------------------------------------------------
// GCN: degree+rsqrt, then flat per-edge norm precompute (bc/bt in place),
// then gather aggregate (wave/node, 2x unrolled)
// ---------------------------------------------------------------------------
__global__ void gcn_deg_dis(const int* __restrict__ offs, const int* __restrict__ csr,
                            const float* __restrict__ bc, const float* __restrict__ bt,
                            float* __restrict__ disc, float* __restrict__ dist)
{
    int n = blockIdx.x * 256 + threadIdx.x;
    if (n >= N_NODES) return;
    int beg = offs[n], end = offs[n + 1];
    float dc = 0.f, dt = 0.f;
    for (int p = beg; p < end; ++p) {
        if (csr[p] & SELF_FLAG) { dc += 1.f; dt += 1.f; }
        else { dc += bc[p]; dt += bt[p]; }
    }
    disc[n] = dc > 0.f ? rsqrtf(fmaxf(dc, 1e-20f)) : 0.f;
    dist[n] = dt > 0.f ? rsqrtf(fmaxf(dt, 1e-20f)) : 0.f;
}

__global__ void gcn_norm(const int* __restrict__ csr, const int* __restrict__ csrd,
                         const float* __restrict__ disc, const float* __restrict__ dist,
                         float* __restrict__ bc, float* __restrict__ bt)
{
    int p = blockIdx.x * 256 + threadIdx.x;
    if (p >= E2) return;
    int sv = csr[p];
    int s = sv & SRC_MASK;
    int d = csrd[p];
    float wc, wt;
    if (sv & SELF_FLAG) { wc = 1.f; wt = 1.f; }
    else { wc = bc[p]; wt = bt[p]; }
    bc[p] = disc[s] * wc * disc[d];
    bt[p] = dist[s] * wt * dist[d];
}

__global__ void gcn_aggregate_n(const int* __restrict__ offs, const int* __restrict__ csr,
                                const float* __restrict__ pre, const float* __restrict__ nrm,
                                float* __restrict__ out)
{
    int n = blockIdx.x * 4 + (threadIdx.x >> 6);
    int lane = threadIdx.x & 63;
    if (n >= N_NODES) return;
    int beg = offs[n], end = offs[n + 1];
    float acc = 0.f;
    int p = beg;
    for (; p + 2 <= end; p += 2) {
        int s0 = csr[p] & SRC_MASK, s1 = csr[p + 1] & SRC_MASK;
        float w0 = nrm[p], w1 = nrm[p + 1];
        float r0 = pre[(size_t)s0 * HD + lane];
        float r1 = pre[(size_t)s1 * HD + lane];
        acc = fmaf(r0, w0, acc);
        acc = fmaf(r1, w1, acc);
    }
    if (p < end) {
        int s0 = csr[p] & SRC_MASK;
        acc = fmaf(pre[(size_t)s0 * HD + lane], nrm[p], acc);
    }
    out[(size_t)n * HD + lane] = acc;
}

// ---------------------------------------------------------------------------
// readout: segment sum of rows by sorted `batch`
// ---------------------------------------------------------------------------
__global__ void readout(const float* __restrict__ Gagg, const int* __restrict__ batch,
                        float* __restrict__ S, float* __restrict__ cnt, int do_cnt)
{
    int chunk = blockIdx.x * 4 + (threadIdx.x >> 6);
    int lane = threadIdx.x & 63;
    int n0 = chunk * 128;
    if (n0 >= N_NODES) return;
    int n1 = n0 + 128; if (n1 > N_NODES) n1 = N_NODES;
    int gp = batch[n0];
    float acc = 0.f; int rc = 0;
    for (int n = n0; n < n1; ++n) {
        int g = batch[n];
        if (g != gp) {
            atomicAdd(&S[gp * 64 + lane], acc);
            if (do_cnt && lane == 0) atomicAdd(&cnt[gp], (float)rc);
            acc = 0.f; rc = 0; gp = g;
        }
        acc += Gagg[(size_t)n * 64 + lane];
        ++rc;
    }
    atomicAdd(&S[gp * 64 + lane], acc);
    if (do_cnt && lane == 0) atomicAdd(&cnt[gp], (float)rc);
}

// ---------------------------------------------------------------------------
// final per-graph heads
// ---------------------------------------------------------------------------
__global__ void final_head(const float* __restrict__ S_c, const float* __restrict__ S_t,
                           const float* __restrict__ cnt,
                           const float* __restrict__ gc_b, const float* __restrict__ gt_b,
                           const float* __restrict__ rc_w, const float* __restrict__ rc_b,
                           const float* __restrict__ rt_w, const float* __restrict__ rt_b,
                           const float* __restrict__ cc_w1, const float* __restrict__ cc_b1,
                           const float* __restrict__ cc_w2, const float* __restrict__ cc_b2,
                           const float* __restrict__ ct_w1, const float* __restrict__ ct_b1,
                           const float* __restrict__ ct_w2, const float* __restrict__ ct_b2,
                           const float* __restrict__ cm_w1, const float* __restrict__ cm_b1,
                           const float* __restrict__ cm_w2, const float* __restrict__ cm_b2,
                           float* __restrict__ out)
{
    int g = blockIdx.x;
    int j = threadIdx.x;
    __shared__ float sc[64], st[64], hgc[64], hgt[64], hid[64];
    float c = cnt[g];
    sc[j] = S_c[g * 64 + j] + c * gc_b[j];
    st[j] = S_t[g * 64 + j] + c * gt_b[j];
    __syncthreads();
    float acr = c * rc_b[j], atr = c * rt_b[j];
#pragma unroll 8
    for (int k = 0; k < 64; ++k) {
        acr = fmaf(sc[k], rc_w[k * 64 + j], acr);
        atr = fmaf(st[k], rt_w[k * 64 + j], atr);
    }
    hgc[j] = acr; hgt[j] = atr;
    out[3840 + g * 64 + j]  = acr;
    out[12032 + g * 64 + j] = atr;
    __syncthreads();
    float hv = 0.f;
    if (j < 32) {
        float a = cc_b1[j];
#pragma unroll 8
        for (int k = 0; k < 64; ++k) a = fmaf(hgc[k], cc_w1[k * 32 + j], a);
        hv = fmaxf(a, 0.f);
    }
    hid[j] = hv;
    __syncthreads();
    if (j < NC) {
        float a = cc_b2[j];
#pragma unroll
        for (int k = 0; k < 32; ++k) a = fmaf(hid[k], cc_w2[k * NC + j], a);
        out[g * NC + j] = a;
    }
    __syncthreads();
    hv = 0.f;
    if (j < 32) {
        float a = ct_b1[j];
#pragma unroll 8
        for (int k = 0; k < 64; ++k) a = fmaf(hgt[k], ct_w1[k * 32 + j], a);
        hv = fmaxf(a, 0.f);
    }
    hid[j] = hv;
    __syncthreads();
    if (j < NC) {
        float a = ct_b2[j];
#pragma unroll
        for (int k = 0; k < 32; ++k) a = fmaf(hid[k], ct_w2[k * NC + j], a);
        out[1280 + g * NC + j] = a;
    }
    __syncthreads();
    {
        float a = cm_b1[j];
#pragma unroll 8
        for (int k = 0; k < 64; ++k) {
            a = fmaf(hgc[k], cm_w1[k * 64 + j], a);
            a = fmaf(hgt[k], cm_w1[(64 + k) * 64 + j], a);
        }
        hid[j] = fmaxf(a, 0.f);
    }
    __syncthreads();
    if (j < NC) {
        float a = cm_b2[j];
#pragma unroll 8
        for (int k = 0; k < 64; ++k) a = fmaf(hid[k], cm_w2[k * NC + j], a);
        out[2560 + g * NC + j] = a;
    }
}

// ---------------------------------------------------------------------------
extern "C" void kernel_launch(void* const* d_in, const int* in_sizes, int n_in,
                              void* d_out, int out_size, void* d_ws, size_t ws_size,
                              hipStream_t stream)
{
    const float* x     = (const float*)d_in[0];
    const int*   ei    = (const int*)d_in[1];
    const int*   batch = (const int*)d_in[2];
    const float* W1    = (const float*)d_in[3];
    const float* as1   = (const float*)d_in[4];
    const float* ad1   = (const float*)d_in[5];
    const float* b1    = (const float*)d_in[6];
    const float* W2    = (const float*)d_in[7];
    const float* as2   = (const float*)d_in[8];
    const float* ad2   = (const float*)d_in[9];
    const float* b2    = (const float*)d_in[10];
    const float* na_w1 = (const float*)d_in[11];
    const float* na_b1 = (const float*)d_in[12];
    const float* na_w2 = (const float*)d_in[13];
    const float* na_b2 = (const float*)d_in[14];
    const float* ea_w1 = (const float*)d_in[15];
    const float* ea_b1 = (const float*)d_in[16];
    const float* ea_w2 = (const float*)d_in[17];
    const float* ea_b2 = (const float*)d_in[18];
    const float* gc_w  = (const float*)d_in[19];
    const float* gc_b  = (const float*)d_in[20];
    const float* gt_w  = (const float*)d_in[21];
    const float* gt_b  = (const float*)d_in[22];
    const float* rc_w  = (const float*)d_in[23];
    const float* rc_b  = (const float*)d_in[24];
    const float* rt_w  = (const float*)d_in[25];
    const float* rt_b  = (const float*)d_in[26];
    const float* cc_w1 = (const float*)d_in[27];
    const float* cc_b1 = (const float*)d_in[28];
    const float* cc_w2 = (const float*)d_in[29];
    const float* cc_b2 = (const float*)d_in[30];
    const float* ct_w1 = (const float*)d_in[31];
    const float* ct_b1 = (const float*)d_in[32];
    const float* ct_w2 = (const float*)d_in[33];
    const float* ct_b2 = (const float*)d_in[34];
    const float* cm_w1 = (const float*)d_in[35];
    const float* cm_b1 = (const float*)d_in[36];
    const float* cm_w2 = (const float*)d_in[37];
    const float* cm_b2 = (const float*)d_in[38];
    float* out = (float*)d_out;

    float* ws = (float*)d_ws;
    size_t o = 0;
    const size_t nf = (size_t)N_NODES * HD;
    float* T0   = ws + o; o += nf;
    float* T1   = ws + o; o += nf;
    float* T2   = ws + o; o += nf;             // H / later reused as agg buffer
    float* es   = ws + o; o += (size_t)N_NODES * NH;
    float* ed   = ws + o; o += (size_t)N_NODES * NH;
    float* ac   = ws + o; o += N_NODES;
    float* at   = ws + o; o += N_NODES;
    float* bc   = ws + o; o += E2;             // beta_c -> (in place) norm_c
    float* bt   = ws + o; o += E2;             // beta_t -> (in place) norm_t
    float* degc = ws + o; o += N_NODES;        // dis_c
    float* degt = ws + o; o += N_NODES;        // dis_t
    float* S_c  = ws + o; o += NG * 64;
    float* S_t  = ws + o; o += NG * 64;
    float* cntf = ws + o; o += NG;
    int* csr    = (int*)(ws + o); o += E2;
    int* csrd   = (int*)(ws + o); o += E2;
    int* offs   = (int*)(ws + o); o += N_NODES + 1;
    int* cnt    = (int*)at;
    int* cursor = (int*)ac;
    int* bsum   = (int*)degc;

    const int NW_BLKS = N_NODES / 4;             // 25000
    const int NT_BLKS = (N_NODES + 255) / 256;   // 391
    const int E_BLKS  = (E2 + 255) / 256;        // 3516
    const int EF_BLKS = (E2 + 31) / 32;          // 28125 (8 lanes/edge, 32 edges/block)
    const int RO_BLKS = ((N_NODES + 127) / 128 + 3) / 4;  // 196

    // ---------------- CSR build ----------------
    hipMemsetAsync(cnt, 0, (size_t)N_NODES * 4, stream);
    csr_hist<<<(E_EDGES + 255) / 256, 256, 0, stream>>>(ei, cnt);
    csr_scan1<<<NSCAN_BLK, 256, 0, stream>>>(cnt, offs, bsum);
    csr_scan2<<<1, 512, 0, stream>>>(bsum);
    csr_scan3<<<NSCAN_BLK, 256, 0, stream>>>(offs, bsum, cursor);
    csr_scatter<<<E_BLKS, 256, 0, stream>>>(ei, cursor, csr, csrd);

    // ---------------- GAT layer 1 ----------------
    gemm_tile<FIN, 1><<<NBLK64, 256, 0, stream>>>(x, W1, T0, as1, ad1, es, ed);
    gat_aggregate<1><<<NW_BLKS, 256, 0, stream>>>(offs, csr, es, ed, T0, b1, T1);

    // ---------------- GAT layer 2 ----------------
    gemm_tile<64, 1><<<NBLK64, 256, 0, stream>>>(T1, W2, T0, as2, ad2, es, ed);
    gat_aggregate<0><<<NW_BLKS, 256, 0, stream>>>(offs, csr, es, ed, T0, b2, T2);

    // ---------------- node attention ----------------
    node_att<<<NW_BLKS, 256, 0, stream>>>(T2, na_w1, na_b1, na_w2, na_b2, ac, at);

    // ---------------- edge attention (P1 -> T1, P2 -> T0) ----------------
    gemm_dual<0><<<NBLK64, 256, 0, stream>>>(T2, ea_w1, ea_w1 + 64 * 64,
                                             nullptr, nullptr, T1, T0);
    edge_att_flat<<<EF_BLKS, 256, 0, stream>>>(csr, csrd, T1, T0, ea_b1, ea_w2, ea_b2, bc, bt);

    // ---------------- GCN norm (bc/bt become per-edge norms in place) -------
    gcn_deg_dis<<<NT_BLKS, 256, 0, stream>>>(offs, csr, bc, bt, degc, degt);
    gcn_norm<<<E_BLKS, 256, 0, stream>>>(csr, csrd, degc, degt, bc, bt);

    hipMemsetAsync(S_c, 0, (size_t)(2 * NG * 64 + NG) * 4, stream);

    // ---------------- GCN pre-transforms (Hc_pre -> T0, Ht_pre -> T1) -------
    gemm_dual<1><<<NBLK64, 256, 0, stream>>>(T2, gc_w, gt_w, ac, at, T0, T1);

    // ---------------- branch c ----------------
    gcn_aggregate_n<<<NW_BLKS, 256, 0, stream>>>(offs, csr, T0, bc, T2);
    readout<<<RO_BLKS, 256, 0, stream>>>(T2, batch, S_c, cntf, 1);

    // ---------------- branch t ----------------
    gcn_aggregate_n<<<NW_BLKS, 256, 0, stream>>>(offs, csr, T1, bt, T2);
    readout<<<RO_BLKS, 256, 0, stream>>>(T2, batch, S_t, cntf, 0);

    // ---------------- heads ----------------
    final_head<<<NG, 64, 0, stream>>>(S_c, S_t, cntf,
                                      gc_b, gt_b, rc_w, rc_b, rt_w, rt_b,
                                      cc_w1, cc_b1, cc_w2, cc_b2,
                                      ct_w1, ct_b1, ct_w2, ct_b2,
                                      cm_w1, cm_b1, cm_w2, cm_b2, out);
    (void)in_sizes; (void)n_in; (void)out_size; (void)ws_size;
}

// Round 5
// 772.718 us; speedup vs baseline: 2.8267x; 1.2271x over previous
//
#include <hip/hip_runtime.h>
#include <hip/hip_bf16.h>

#define N_NODES 100000
#define E_EDGES 800000
#define E2 (E_EDGES + N_NODES)   // 900000 edges incl. self loops
#define FIN 128
#define HD 64
#define NH 8
#define NG 128
#define NC 10
#define SLOPE 0.2f
#define SELF_FLAG 0x40000000
#define SRC_MASK  0x3FFFFFFF
#define NSCAN_BLK 391            // ceil(N/256)
#define NBLK64 1563              // ceil(N/64)

__device__ __forceinline__ float lrelu(float x) { return x > 0.f ? x : SLOPE * x; }

// ---------------------------------------------------------------------------
// Tiled node GEMM: 64 nodes/block, thread = 4 nodes x 4 outputs.
// MODE 0: plain. MODE 1: es/ed head-dot epilogue.
// ---------------------------------------------------------------------------
template<int KIN, int MODE>
__global__ __launch_bounds__(256)
void gemm_tile(const float* __restrict__ in, const float* __restrict__ W,
               float* __restrict__ out,
               const float* __restrict__ a_s, const float* __restrict__ a_d,
               float* __restrict__ es, float* __restrict__ ed)
{
    __shared__ float Ws[KIN * 64];
    __shared__ float rows[64 * (KIN + 1)];
    int t = threadIdx.x;
    int base = blockIdx.x * 64;
    {
        const float4* Wv = (const float4*)W;
        float4* Wsv = (float4*)Ws;
        for (int i = t; i < KIN * 16; i += 256) Wsv[i] = Wv[i];
    }
    constexpr int RQ = KIN / 4;
    for (int i = t; i < 64 * RQ; i += 256) {
        int r = i / RQ, c = (i % RQ) * 4;
        int n = base + r;
        float4 v = make_float4(0.f, 0.f, 0.f, 0.f);
        if (n < N_NODES) v = *(const float4*)(in + (size_t)n * KIN + c);
        float* dp = rows + r * (KIN + 1) + c;
        dp[0] = v.x; dp[1] = v.y; dp[2] = v.z; dp[3] = v.w;
    }
    __syncthreads();
    int tr = t >> 4, tc = t & 15;
    float acc[4][4] = {};
    const float4* Wsv = (const float4*)Ws;
#pragma unroll 8
    for (int k = 0; k < KIN; ++k) {
        float4 w = Wsv[k * 16 + tc];
        float rv[4];
#pragma unroll
        for (int i = 0; i < 4; ++i) rv[i] = rows[(tr * 4 + i) * (KIN + 1) + k];
#pragma unroll
        for (int i = 0; i < 4; ++i) {
            acc[i][0] = fmaf(rv[i], w.x, acc[i][0]);
            acc[i][1] = fmaf(rv[i], w.y, acc[i][1]);
            acc[i][2] = fmaf(rv[i], w.z, acc[i][2]);
            acc[i][3] = fmaf(rv[i], w.w, acc[i][3]);
        }
    }
    int j0 = tc * 4;
#pragma unroll
    for (int i = 0; i < 4; ++i) {
        int n = base + tr * 4 + i;
        if (n < N_NODES)
            *(float4*)(out + (size_t)n * 64 + j0) =
                make_float4(acc[i][0], acc[i][1], acc[i][2], acc[i][3]);
    }
    if (MODE == 1) {
        float s0[4], s1[4];
#pragma unroll
        for (int i = 0; i < 4; ++i) {
            float pes = 0.f, ped = 0.f;
#pragma unroll
            for (int q = 0; q < 4; ++q) {
                pes = fmaf(acc[i][q], a_s[j0 + q], pes);
                ped = fmaf(acc[i][q], a_d[j0 + q], ped);
            }
            pes += __shfl_xor(pes, 1, 64);
            ped += __shfl_xor(ped, 1, 64);
            s0[i] = pes; s1[i] = ped;
        }
        if ((tc & 1) == 0) {
            int h = tc >> 1;
#pragma unroll
            for (int i = 0; i < 4; ++i) {
                int n = base + tr * 4 + i;
                if (n < N_NODES) {
                    es[n * NH + h] = s0[i];
                    ed[n * NH + h] = s1[i];
                }
            }
        }
    }
}

// ---------------------------------------------------------------------------
// Dual node GEMM (shared input, two weight mats). SCALED: out_i *= sc_i[n].
// ---------------------------------------------------------------------------
template<int SCALED>
__global__ __launch_bounds__(256)
void gemm_dual(const float* __restrict__ in, const float* __restrict__ W0,
               const float* __restrict__ W1,
               const float* __restrict__ sc0, const float* __restrict__ sc1,
               float* __restrict__ out0, float* __restrict__ out1)
{
    __shared__ float Ws[2 * 64 * 64];
    __shared__ float rows[64 * 65];
    int t = threadIdx.x;
    int base = blockIdx.x * 64;
    {
        const float4* W0v = (const float4*)W0;
        const float4* W1v = (const float4*)W1;
        float4* Wsv = (float4*)Ws;
        for (int i = t; i < 1024; i += 256) { Wsv[i] = W0v[i]; Wsv[1024 + i] = W1v[i]; }
    }
    for (int i = t; i < 64 * 16; i += 256) {
        int r = i / 16, c = (i % 16) * 4;
        int n = base + r;
        float4 v = make_float4(0.f, 0.f, 0.f, 0.f);
        if (n < N_NODES) v = *(const float4*)(in + (size_t)n * 64 + c);
        float* dp = rows + r * 65 + c;
        dp[0] = v.x; dp[1] = v.y; dp[2] = v.z; dp[3] = v.w;
    }
    __syncthreads();
    int tr = t >> 4, tc = t & 15;
    float a0[4][4] = {}, a1[4][4] = {};
    const float4* Wsv = (const float4*)Ws;
#pragma unroll 4
    for (int k = 0; k < 64; ++k) {
        float4 w0 = Wsv[k * 16 + tc];
        float4 w1 = Wsv[1024 + k * 16 + tc];
        float rv[4];
#pragma unroll
        for (int i = 0; i < 4; ++i) rv[i] = rows[(tr * 4 + i) * 65 + k];
#pragma unroll
        for (int i = 0; i < 4; ++i) {
            a0[i][0] = fmaf(rv[i], w0.x, a0[i][0]);
            a0[i][1] = fmaf(rv[i], w0.y, a0[i][1]);
            a0[i][2] = fmaf(rv[i], w0.z, a0[i][2]);
            a0[i][3] = fmaf(rv[i], w0.w, a0[i][3]);
            a1[i][0] = fmaf(rv[i], w1.x, a1[i][0]);
            a1[i][1] = fmaf(rv[i], w1.y, a1[i][1]);
            a1[i][2] = fmaf(rv[i], w1.z, a1[i][2]);
            a1[i][3] = fmaf(rv[i], w1.w, a1[i][3]);
        }
    }
    int j0 = tc * 4;
#pragma unroll
    for (int i = 0; i < 4; ++i) {
        int n = base + tr * 4 + i;
        if (n >= N_NODES) continue;
        float m0 = 1.f, m1 = 1.f;
        if (SCALED) { m0 = sc0[n]; m1 = sc1[n]; }
        *(float4*)(out0 + (size_t)n * 64 + j0) =
            make_float4(a0[i][0] * m0, a0[i][1] * m0, a0[i][2] * m0, a0[i][3] * m0);
        *(float4*)(out1 + (size_t)n * 64 + j0) =
            make_float4(a1[i][0] * m1, a1[i][1] * m1, a1[i][2] * m1, a1[i][3] * m1);
    }
}

// ---------------------------------------------------------------------------
// CSR build: histogram -> scan -> scatter (+ dst array)
// ---------------------------------------------------------------------------
__global__ void csr_hist(const int* __restrict__ ei, int* __restrict__ cnt)
{
    int e = blockIdx.x * 256 + threadIdx.x;
    if (e >= E_EDGES) return;
    atomicAdd(&cnt[ei[E_EDGES + e]], 1);
}

__global__ void csr_scan1(const int* __restrict__ cnt, int* __restrict__ offs,
                          int* __restrict__ bsum)
{
    __shared__ int tmp[256];
    int t = threadIdx.x;
    int i = blockIdx.x * 256 + t;
    int v = (i < N_NODES) ? cnt[i] + 1 : 0;
    tmp[t] = v; __syncthreads();
#pragma unroll
    for (int o = 1; o < 256; o <<= 1) {
        int a = (t >= o) ? tmp[t - o] : 0;
        __syncthreads();
        tmp[t] += a;
        __syncthreads();
    }
    if (i < N_NODES) offs[i] = tmp[t] - v;
    if (t == 255) bsum[blockIdx.x] = tmp[255];
}

__global__ void csr_scan2(int* __restrict__ bsum)
{
    __shared__ int tmp[512];
    int t = threadIdx.x;
    int v = (t < NSCAN_BLK) ? bsum[t] : 0;
    tmp[t] = v; __syncthreads();
#pragma unroll
    for (int o = 1; o < 512; o <<= 1) {
        int a = (t >= o) ? tmp[t - o] : 0;
        __syncthreads();
        tmp[t] += a;
        __syncthreads();
    }
    if (t < NSCAN_BLK) bsum[t] = tmp[t] - v;
}

__global__ void csr_scan3(int* __restrict__ offs, const int* __restrict__ bsum,
                          int* __restrict__ cursor)
{
    int i = blockIdx.x * 256 + threadIdx.x;
    if (i < N_NODES) {
        int v = offs[i] + bsum[blockIdx.x];
        offs[i] = v;
        cursor[i] = v;
    }
    if (i == 0) offs[N_NODES] = E2;
}

__global__ void csr_scatter(const int* __restrict__ ei, int* __restrict__ cursor,
                            int* __restrict__ csr, int* __restrict__ csrd)
{
    int e = blockIdx.x * 256 + threadIdx.x;
    if (e >= E2) return;
    int d, tag;
    if (e < E_EDGES) { int s = ei[e]; d = ei[E_EDGES + e]; tag = s; }
    else             { d = e - E_EDGES; tag = d | SELF_FLAG; }
    int pos = atomicAdd(&cursor[d], 1);
    csr[pos] = tag;
    csrd[pos] = d;
}

// ---------------------------------------------------------------------------
// Fused GAT aggregate: wave per dst node; 4 edge-slots x 16 feature-lanes.
// Each feature-lane holds float4 (4 features); head h = fl>>1.
// ---------------------------------------------------------------------------
template<int ELU>
__global__ void gat_aggregate4(const int* __restrict__ offs, const int* __restrict__ csr,
                               const float* __restrict__ es, const float* __restrict__ ed,
                               const float* __restrict__ hsrc, const float* __restrict__ bias,
                               float* __restrict__ out)
{
    int n = blockIdx.x * 4 + (threadIdx.x >> 6);
    int lane = threadIdx.x & 63;
    if (n >= N_NODES) return;
    int g  = lane >> 4;        // edge slot 0..3
    int fl = lane & 15;        // feature chunk: features fl*4 .. fl*4+3
    int h  = fl >> 1;          // head
    int beg = offs[n], end = offs[n + 1];
    float edv = ed[n * NH + h];
    // pass 1: max over incoming edges (strided by slot)
    float mh = -1e30f;
    for (int p = beg + g; p < end; p += 4) {
        int s = csr[p] & SRC_MASK;
        mh = fmaxf(mh, lrelu(es[s * NH + h] + edv));
    }
    mh = fmaxf(mh, __shfl_xor(mh, 16, 64));
    mh = fmaxf(mh, __shfl_xor(mh, 32, 64));
    // pass 2: exp-sum + weighted feature gather (4 rows in flight per wave)
    float den = 0.f;
    float4 acc = make_float4(0.f, 0.f, 0.f, 0.f);
    for (int p = beg + g; p < end; p += 4) {
        int s = csr[p] & SRC_MASK;
        float l = lrelu(es[s * NH + h] + edv);
        float ex = __expf(l - mh);
        den += ex;
        float4 r = *(const float4*)(hsrc + (size_t)s * HD + fl * 4);
        acc.x = fmaf(r.x, ex, acc.x);
        acc.y = fmaf(r.y, ex, acc.y);
        acc.z = fmaf(r.z, ex, acc.z);
        acc.w = fmaf(r.w, ex, acc.w);
    }
#pragma unroll
    for (int o = 16; o <= 32; o <<= 1) {
        den   += __shfl_xor(den,   o, 64);
        acc.x += __shfl_xor(acc.x, o, 64);
        acc.y += __shfl_xor(acc.y, o, 64);
        acc.z += __shfl_xor(acc.z, o, 64);
        acc.w += __shfl_xor(acc.w, o, 64);
    }
    if (g == 0) {
        float inv = 1.f / (den + 1e-16f);
        float4 bv = *(const float4*)(bias + fl * 4);
        float v0 = acc.x * inv + bv.x;
        float v1 = acc.y * inv + bv.y;
        float v2 = acc.z * inv + bv.z;
        float v3 = acc.w * inv + bv.w;
        if (ELU) {
            v0 = v0 > 0.f ? v0 : (__expf(v0) - 1.f);
            v1 = v1 > 0.f ? v1 : (__expf(v1) - 1.f);
            v2 = v2 > 0.f ? v2 : (__expf(v2) - 1.f);
            v3 = v3 > 0.f ? v3 : (__expf(v3) - 1.f);
        }
        *(float4*)(out + (size_t)n * HD + fl * 4) = make_float4(v0, v1, v2, v3);
    }
}

// ---------------------------------------------------------------------------
// node attention, tiled: 64 nodes/block, w1+rows staged in LDS.
// thread = 2 nodes x 4 hidden; 3-step shuffle reduce for z.
// ---------------------------------------------------------------------------
__global__ __launch_bounds__(256)
void node_att_tile(const float* __restrict__ H, const float* __restrict__ w1,
                   const float* __restrict__ b1, const float* __restrict__ w2,
                   const float* __restrict__ b2, float* __restrict__ ac,
                   float* __restrict__ at)
{
    __shared__ float w1s[64 * 32];
    __shared__ float w2s[64];
    __shared__ float rows[64 * 65];
    int t = threadIdx.x;
    int base = blockIdx.x * 64;
    {
        const float4* w1v = (const float4*)w1;
        float4* dst = (float4*)w1s;
        for (int i = t; i < 512; i += 256) dst[i] = w1v[i];
    }
    if (t < 64) w2s[t] = w2[t];
    for (int i = t; i < 64 * 16; i += 256) {
        int r = i >> 4, c = (i & 15) * 4;
        int n = base + r;
        float4 v = make_float4(0.f, 0.f, 0.f, 0.f);
        if (n < N_NODES) v = *(const float4*)(H + (size_t)n * 64 + c);
        float* dp = rows + r * 65 + c;
        dp[0] = v.x; dp[1] = v.y; dp[2] = v.z; dp[3] = v.w;
    }
    __syncthreads();
    int tr = t >> 3;   // 0..31 -> nodes tr, tr+32
    int tc = t & 7;    // hidden group: j = tc*4 .. tc*4+3
    float4 bv = *(const float4*)(b1 + tc * 4);
    float4 acc0 = bv, acc1 = bv;
    const float4* w1sv = (const float4*)w1s;
#pragma unroll 8
    for (int k = 0; k < 64; ++k) {
        float4 w = w1sv[k * 8 + tc];
        float r0 = rows[tr * 65 + k];
        float r1 = rows[(tr + 32) * 65 + k];
        acc0.x = fmaf(r0, w.x, acc0.x); acc0.y = fmaf(r0, w.y, acc0.y);
        acc0.z = fmaf(r0, w.z, acc0.z); acc0.w = fmaf(r0, w.w, acc0.w);
        acc1.x = fmaf(r1, w.x, acc1.x); acc1.y = fmaf(r1, w.y, acc1.y);
        acc1.z = fmaf(r1, w.z, acc1.z); acc1.w = fmaf(r1, w.w, acc1.w);
    }
    float z00 = 0.f, z01 = 0.f, z10 = 0.f, z11 = 0.f;
    float h0, w20, w21;
    int j0 = tc * 4;
#pragma unroll
    for (int q = 0; q < 4; ++q) {
        float a0q = q == 0 ? acc0.x : q == 1 ? acc0.y : q == 2 ? acc0.z : acc0.w;
        float a1q = q == 0 ? acc1.x : q == 1 ? acc1.y : q == 2 ? acc1.z : acc1.w;
        w20 = w2s[(j0 + q) * 2]; w21 = w2s[(j0 + q) * 2 + 1];
        h0 = fmaxf(a0q, 0.f);
        z00 = fmaf(h0, w20, z00); z01 = fmaf(h0, w21, z01);
        h0 = fmaxf(a1q, 0.f);
        z10 = fmaf(h0, w20, z10); z11 = fmaf(h0, w21, z11);
    }
#pragma unroll
    for (int o = 1; o < 8; o <<= 1) {
        z00 += __shfl_xor(z00, o, 64); z01 += __shfl_xor(z01, o, 64);
        z10 += __shfl_xor(z10, o, 64); z11 += __shfl_xor(z11, o, 64);
    }
    if (tc == 0) {
        int n0 = base + tr, n1 = base + tr + 32;
        if (n0 < N_NODES) {
            float zz0 = z00 + b2[0], zz1 = z01 + b2[1];
            float mx = fmaxf(zz0, zz1);
            float e0 = __expf(zz0 - mx), e1 = __expf(zz1 - mx);
            float ss = e0 + e1;
            ac[n0] = e0 / ss; at[n0] = e1 / ss;
        }
        if (n1 < N_NODES) {
            float zz0 = z10 + b2[0], zz1 = z11 + b2[1];
            float mx = fmaxf(zz0, zz1);
            float e0 = __expf(zz0 - mx), e1 = __expf(zz1 - mx);
            float ss = e0 + e1;
            ac[n1] = e0 / ss; at[n1] = e1 / ss;
        }
    }
}

// ---------------------------------------------------------------------------
// edge attention, flat over CSR positions: 8 lanes per edge, 8 edges per wave
// ---------------------------------------------------------------------------
__global__ __launch_bounds__(256)
void edge_att_flat(const int* __restrict__ csr, const int* __restrict__ csrd,
                   const float* __restrict__ P1, const float* __restrict__ P2,
                   const float* __restrict__ b1, const float* __restrict__ w2,
                   const float* __restrict__ b2,
                   float* __restrict__ bc, float* __restrict__ bt)
{
    int lane = threadIdx.x & 63;
    int sg = lane >> 3, q = lane & 7;
    int p = (blockIdx.x * 4 + (threadIdx.x >> 6)) * 8 + sg;
    if (p >= E2) return;
    int sv = csr[p];
    if (sv & SELF_FLAG) return;
    int d = csrd[p];
    const float4* pu = (const float4*)(P1 + (size_t)sv * 64 + q * 8);
    const float4* pv = (const float4*)(P2 + (size_t)d * 64 + q * 8);
    const float4* pb = (const float4*)(b1 + q * 8);
    const float4* pw = (const float4*)(w2 + q * 16);
    float4 u0 = pu[0], u1 = pu[1];
    float4 v0 = pv[0], v1 = pv[1];
    float4 c0 = pb[0], c1 = pb[1];
    float4 w0 = pw[0], w1v = pw[1], w2v = pw[2], w3v = pw[3];
    float h0 = fmaxf(u0.x + v0.x + c0.x, 0.f);
    float h1 = fmaxf(u0.y + v0.y + c0.y, 0.f);
    float h2 = fmaxf(u0.z + v0.z + c0.z, 0.f);
    float h3 = fmaxf(u0.w + v0.w + c0.w, 0.f);
    float h4 = fmaxf(u1.x + v1.x + c1.x, 0.f);
    float h5 = fmaxf(u1.y + v1.y + c1.y, 0.f);
    float h6 = fmaxf(u1.z + v1.z + c1.z, 0.f);
    float h7 = fmaxf(u1.w + v1.w + c1.w, 0.f);
    float z0 = h0 * w0.x + h1 * w0.z + h2 * w1v.x + h3 * w1v.z
             + h4 * w2v.x + h5 * w2v.z + h6 * w3v.x + h7 * w3v.z;
    float z1 = h0 * w0.y + h1 * w0.w + h2 * w1v.y + h3 * w1v.w
             + h4 * w2v.y + h5 * w2v.w + h6 * w3v.y + h7 * w3v.w;
    z0 += __shfl_xor(z0, 1, 64); z1 += __shfl_xor(z1, 1, 64);
    z0 += __shfl_xor(z0, 2, 64); z1 += __shfl_xor(z1, 2, 64);
    z0 += __shfl_xor(z0, 4, 64); z1 += __shfl_xor(z1, 4, 64);
    if (q == 0) {
        z0 += b2[0]; z1 += b2[1];
        float mx = fmaxf(z0, z1);
        float e0 = __expf(z0 - mx), e1 = __expf(z1 - mx);
        float ss = e0 + e1;
        bc[p] = e0 / ss;
        bt[p] = e1 / ss;
    }
}

// ---------------------------------------------------------------------------
// GCN: degree+rsqrt, flat per-edge norm precompute, gather aggregate (4-slot)
// ---------------------------------------------------------------------------
__global__ void gcn_deg_dis(const int* __restrict__ offs, const int* __restrict__ csr,
                            const float* __restrict__ bc, const float* __restrict__ bt,
                            float* __restrict__ disc, float* __restrict__ dist)
{
    int n = blockIdx.x * 256 + threadIdx.x;
    if (n >= N_NODES) return;
    int beg = offs[n], end = offs[n + 1];
    float dc = 0.f, dt = 0.f;
    for (int p = beg; p < end; ++p) {
        if (csr[p] & SELF_FLAG) { dc += 1.f; dt += 1.f; }
        else { dc += bc[p]; dt += bt[p]; }
    }
    disc[n] = dc > 0.f ? rsqrtf(fmaxf(dc, 1e-20f)) : 0.f;
    dist[n] = dt > 0.f ? rsqrtf(fmaxf(dt, 1e-20f)) : 0.f;
}

__global__ void gcn_norm(const int* __restrict__ csr, const int* __restrict__ csrd,
                         const float* __restrict__ disc, const float* __restrict__ dist,
                         float* __restrict__ bc, float* __restrict__ bt)
{
    int p = blockIdx.x * 256 + threadIdx.x;
    if (p >= E2) return;
    int sv = csr[p];
    int s = sv & SRC_MASK;
    int d = csrd[p];
    float wc, wt;
    if (sv & SELF_FLAG) { wc = 1.f; wt = 1.f; }
    else { wc = bc[p]; wt = bt[p]; }
    bc[p] = disc[s] * wc * disc[d];
    bt[p] = dist[s] * wt * dist[d];
}

__global__ void gcn_aggregate4(const int* __restrict__ offs, const int* __restrict__ csr,
                               const float* __restrict__ pre, const float* __restrict__ nrm,
                               float* __restrict__ out)
{
    int n = blockIdx.x * 4 + (threadIdx.x >> 6);
    int lane = threadIdx.x & 63;
    if (n >= N_NODES) return;
    int g  = lane >> 4;
    int fl = lane & 15;
    int beg = offs[n], end = offs[n + 1];
    float4 acc = make_float4(0.f, 0.f, 0.f, 0.f);
    for (int p = beg + g; p < end; p += 4) {
        int s = csr[p] & SRC_MASK;
        float w = nrm[p];
        float4 r = *(const float4*)(pre + (size_t)s * HD + fl * 4);
        acc.x = fmaf(r.x, w, acc.x);
        acc.y = fmaf(r.y, w, acc.y);
        acc.z = fmaf(r.z, w, acc.z);
        acc.w = fmaf(r.w, w, acc.w);
    }
#pragma unroll
    for (int o = 16; o <= 32; o <<= 1) {
        acc.x += __shfl_xor(acc.x, o, 64);
        acc.y += __shfl_xor(acc.y, o, 64);
        acc.z += __shfl_xor(acc.z, o, 64);
        acc.w += __shfl_xor(acc.w, o, 64);
    }
    if (g == 0)
        *(float4*)(out + (size_t)n * HD + fl * 4) = acc;
}

// ---------------------------------------------------------------------------
// readout: segment sum of rows by sorted `batch`
// ---------------------------------------------------------------------------
__global__ void readout(const float* __restrict__ Gagg, const int* __restrict__ batch,
                        float* __restrict__ S, float* __restrict__ cnt, int do_cnt)
{
    int chunk = blockIdx.x * 4 + (threadIdx.x >> 6);
    int lane = threadIdx.x & 63;
    int n0 = chunk * 128;
    if (n0 >= N_NODES) return;
    int n1 = n0 + 128; if (n1 > N_NODES) n1 = N_NODES;
    int gp = batch[n0];
    float acc = 0.f; int rc = 0;
    for (int n = n0; n < n1; ++n) {
        int g = batch[n];
        if (g != gp) {
            atomicAdd(&S[gp * 64 + lane], acc);
            if (do_cnt && lane == 0) atomicAdd(&cnt[gp], (float)rc);
            acc = 0.f; rc = 0; gp = g;
        }
        acc += Gagg[(size_t)n * 64 + lane];
        ++rc;
    }
    atomicAdd(&S[gp * 64 + lane], acc);
    if (do_cnt && lane == 0) atomicAdd(&cnt[gp], (float)rc);
}

// ---------------------------------------------------------------------------
// final per-graph heads
// ---------------------------------------------------------------------------
__global__ void final_head(const float* __restrict__ S_c, const float* __restrict__ S_t,
                           const float* __restrict__ cnt,
                           const float* __restrict__ gc_b, const float* __restrict__ gt_b,
                           const float* __restrict__ rc_w, const float* __restrict__ rc_b,
                           const float* __restrict__ rt_w, const float* __restrict__ rt_b,
                           const float* __restrict__ cc_w1, const float* __restrict__ cc_b1,
                           const float* __restrict__ cc_w2, const float* __restrict__ cc_b2,
                           const float* __restrict__ ct_w1, const float* __restrict__ ct_b1,
                           const float* __restrict__ ct_w2, const float* __restrict__ ct_b2,
                           const float* __restrict__ cm_w1, const float* __restrict__ cm_b1,
                           const float* __restrict__ cm_w2, const float* __restrict__ cm_b2,
                           float* __restrict__ out)
{
    int g = blockIdx.x;
    int j = threadIdx.x;
    __shared__ float sc[64], st[64], hgc[64], hgt[64], hid[64];
    float c = cnt[g];
    sc[j] = S_c[g * 64 + j] + c * gc_b[j];
    st[j] = S_t[g * 64 + j] + c * gt_b[j];
    __syncthreads();
    float acr = c * rc_b[j], atr = c * rt_b[j];
#pragma unroll 8
    for (int k = 0; k < 64; ++k) {
        acr = fmaf(sc[k], rc_w[k * 64 + j], acr);
        atr = fmaf(st[k], rt_w[k * 64 + j], atr);
    }
    hgc[j] = acr; hgt[j] = atr;
    out[3840 + g * 64 + j]  = acr;
    out[12032 + g * 64 + j] = atr;
    __syncthreads();
    float hv = 0.f;
    if (j < 32) {
        float a = cc_b1[j];
#pragma unroll 8
        for (int k = 0; k < 64; ++k) a = fmaf(hgc[k], cc_w1[k * 32 + j], a);
        hv = fmaxf(a, 0.f);
    }
    hid[j] = hv;
    __syncthreads();
    if (j < NC) {
        float a = cc_b2[j];
#pragma unroll
        for (int k = 0; k < 32; ++k) a = fmaf(hid[k], cc_w2[k * NC + j], a);
        out[g * NC + j] = a;
    }
    __syncthreads();
    hv = 0.f;
    if (j < 32) {
        float a = ct_b1[j];
#pragma unroll 8
        for (int k = 0; k < 64; ++k) a = fmaf(hgt[k], ct_w1[k * 32 + j], a);
        hv = fmaxf(a, 0.f);
    }
    hid[j] = hv;
    __syncthreads();
    if (j < NC) {
        float a = ct_b2[j];
#pragma unroll
        for (int k = 0; k < 32; ++k) a = fmaf(hid[k], ct_w2[k * NC + j], a);
        out[1280 + g * NC + j] = a;
    }
    __syncthreads();
    {
        float a = cm_b1[j];
#pragma unroll 8
        for (int k = 0; k < 64; ++k) {
            a = fmaf(hgc[k], cm_w1[k * 64 + j], a);
            a = fmaf(hgt[k], cm_w1[(64 + k) * 64 + j], a);
        }
        hid[j] = fmaxf(a, 0.f);
    }
    __syncthreads();
    if (j < NC) {
        float a = cm_b2[j];
#pragma unroll 8
        for (int k = 0; k < 64; ++k) a = fmaf(hid[k], cm_w2[k * NC + j], a);
        out[2560 + g * NC + j] = a;
    }
}

// ---------------------------------------------------------------------------
extern "C" void kernel_launch(void* const* d_in, const int* in_sizes, int n_in,
                              void* d_out, int out_size, void* d_ws, size_t ws_size,
                              hipStream_t stream)
{
    const float* x     = (const float*)d_in[0];
    const int*   ei    = (const int*)d_in[1];
    const int*   batch = (const int*)d_in[2];
    const float* W1    = (const float*)d_in[3];
    const float* as1   = (const float*)d_in[4];
    const float* ad1   = (const float*)d_in[5];
    const float* b1    = (const float*)d_in[6];
    const float* W2    = (const float*)d_in[7];
    const float* as2   = (const float*)d_in[8];
    const float* ad2   = (const float*)d_in[9];
    const float* b2    = (const float*)d_in[10];
    const float* na_w1 = (const float*)d_in[11];
    const float* na_b1 = (const float*)d_in[12];
    const float* na_w2 = (const float*)d_in[13];
    const float* na_b2 = (const float*)d_in[14];
    const float* ea_w1 = (const float*)d_in[15];
    const float* ea_b1 = (const float*)d_in[16];
    const float* ea_w2 = (const float*)d_in[17];
    const float* ea_b2 = (const float*)d_in[18];
    const float* gc_w  = (const float*)d_in[19];
    const float* gc_b  = (const float*)d_in[20];
    const float* gt_w  = (const float*)d_in[21];
    const float* gt_b  = (const float*)d_in[22];
    const float* rc_w  = (const float*)d_in[23];
    const float* rc_b  = (const float*)d_in[24];
    const float* rt_w  = (const float*)d_in[25];
    const float* rt_b  = (const float*)d_in[26];
    const float* cc_w1 = (const float*)d_in[27];
    const float* cc_b1 = (const float*)d_in[28];
    const float* cc_w2 = (const float*)d_in[29];
    const float* cc_b2 = (const float*)d_in[30];
    const float* ct_w1 = (const float*)d_in[31];
    const float* ct_b1 = (const float*)d_in[32];
    const float* ct_w2 = (const float*)d_in[33];
    const float* ct_b2 = (const float*)d_in[34];
    const float* cm_w1 = (const float*)d_in[35];
    const float* cm_b1 = (const float*)d_in[36];
    const float* cm_w2 = (const float*)d_in[37];
    const float* cm_b2 = (const float*)d_in[38];
    float* out = (float*)d_out;

    float* ws = (float*)d_ws;
    size_t o = 0;
    const size_t nf = (size_t)N_NODES * HD;
    float* T0   = ws + o; o += nf;
    float* T1   = ws + o; o += nf;
    float* T2   = ws + o; o += nf;             // H / later reused as agg buffer
    float* es   = ws + o; o += (size_t)N_NODES * NH;
    float* ed   = ws + o; o += (size_t)N_NODES * NH;
    float* ac   = ws + o; o += N_NODES;
    float* at   = ws + o; o += N_NODES;
    float* bc   = ws + o; o += E2;             // beta_c -> (in place) norm_c
    float* bt   = ws + o; o += E2;             // beta_t -> (in place) norm_t
    float* degc = ws + o; o += N_NODES;        // dis_c
    float* degt = ws + o; o += N_NODES;        // dis_t
    float* S_c  = ws + o; o += NG * 64;
    float* S_t  = ws + o; o += NG * 64;
    float* cntf = ws + o; o += NG;
    int* csr    = (int*)(ws + o); o += E2;
    int* csrd   = (int*)(ws + o); o += E2;
    int* offs   = (int*)(ws + o); o += N_NODES + 1;
    int* cnt    = (int*)at;
    int* cursor = (int*)ac;
    int* bsum   = (int*)degc;

    const int NW_BLKS = N_NODES / 4;             // 25000
    const int NT_BLKS = (N_NODES + 255) / 256;   // 391
    const int E_BLKS  = (E2 + 255) / 256;        // 3516
    const int EF_BLKS = (E2 + 31) / 32;          // 28125
    const int RO_BLKS = ((N_NODES + 127) / 128 + 3) / 4;  // 196

    // ---------------- CSR build ----------------
    hipMemsetAsync(cnt, 0, (size_t)N_NODES * 4, stream);
    csr_hist<<<(E_EDGES + 255) / 256, 256, 0, stream>>>(ei, cnt);
    csr_scan1<<<NSCAN_BLK, 256, 0, stream>>>(cnt, offs, bsum);
    csr_scan2<<<1, 512, 0, stream>>>(bsum);
    csr_scan3<<<NSCAN_BLK, 256, 0, stream>>>(offs, bsum, cursor);
    csr_scatter<<<E_BLKS, 256, 0, stream>>>(ei, cursor, csr, csrd);

    // ---------------- GAT layer 1 ----------------
    gemm_tile<FIN, 1><<<NBLK64, 256, 0, stream>>>(x, W1, T0, as1, ad1, es, ed);
    gat_aggregate4<1><<<NW_BLKS, 256, 0, stream>>>(offs, csr, es, ed, T0, b1, T1);

    // ---------------- GAT layer 2 ----------------
    gemm_tile<64, 1><<<NBLK64, 256, 0, stream>>>(T1, W2, T0, as2, ad2, es, ed);
    gat_aggregate4<0><<<NW_BLKS, 256, 0, stream>>>(offs, csr, es, ed, T0, b2, T2);

    // ---------------- node attention ----------------
    node_att_tile<<<NBLK64, 256, 0, stream>>>(T2, na_w1, na_b1, na_w2, na_b2, ac, at);

    // ---------------- edge attention (P1 -> T1, P2 -> T0) ----------------
    gemm_dual<0><<<NBLK64, 256, 0, stream>>>(T2, ea_w1, ea_w1 + 64 * 64,
                                             nullptr, nullptr, T1, T0);
    edge_att_flat<<<EF_BLKS, 256, 0, stream>>>(csr, csrd, T1, T0, ea_b1, ea_w2, ea_b2, bc, bt);

    // ---------------- GCN norm (bc/bt become per-edge norms in place) -------
    gcn_deg_dis<<<NT_BLKS, 256, 0, stream>>>(offs, csr, bc, bt, degc, degt);
    gcn_norm<<<E_BLKS, 256, 0, stream>>>(csr, csrd, degc, degt, bc, bt);

    hipMemsetAsync(S_c, 0, (size_t)(2 * NG * 64 + NG) * 4, stream);

    // ---------------- GCN pre-transforms (Hc_pre -> T0, Ht_pre -> T1) -------
    gemm_dual<1><<<NBLK64, 256, 0, stream>>>(T2, gc_w, gt_w, ac, at, T0, T1);

    // ---------------- branch c ----------------
    gcn_aggregate4<<<NW_BLKS, 256, 0, stream>>>(offs, csr, T0, bc, T2);
    readout<<<RO_BLKS, 256, 0, stream>>>(T2, batch, S_c, cntf, 1);

    // ---------------- branch t ----------------
    gcn_aggregate4<<<NW_BLKS, 256, 0, stream>>>(offs, csr, T1, bt, T2);
    readout<<<RO_BLKS, 256, 0, stream>>>(T2, batch, S_t, cntf, 0);

    // ---------------- heads ----------------
    final_head<<<NG, 64, 0, stream>>>(S_c, S_t, cntf,
                                      gc_b, gt_b, rc_w, rc_b, rt_w, rt_b,
                                      cc_w1, cc_b1, cc_w2, cc_b2,
                                      ct_w1, ct_b1, ct_w2, ct_b2,
                                      cm_w1, cm_b1, cm_w2, cm_b2, out);
    (void)in_sizes; (void)n_in; (void)out_size; (void)ws_size;
}

// Round 6
// 650.408 us; speedup vs baseline: 3.3583x; 1.1881x over previous
//
#include <hip/hip_runtime.h>
#include <hip/hip_bf16.h>

#define N_NODES 100000
#define E_EDGES 800000
#define E2 (E_EDGES + N_NODES)   // 900000 edges incl. self loops
#define FIN 128
#define HD 64
#define NH 8
#define NG 128
#define NC 10
#define SLOPE 0.2f
#define SELF_FLAG 0x40000000
#define SRC_MASK  0x3FFFFFFF
#define NSCAN_BLK 391            // ceil(N/256)
#define NBLK64 1563              // ceil(N/64)

typedef unsigned short bfu;

__device__ __forceinline__ float lrelu(float x) { return x > 0.f ? x : SLOPE * x; }

__device__ __forceinline__ bfu f2bf(float f) {
    unsigned int u = __float_as_uint(f);
    u += 0x7FFFu + ((u >> 16) & 1u);          // round-to-nearest-even
    return (bfu)(u >> 16);
}
__device__ __forceinline__ float bf2f(bfu s) {
    return __uint_as_float(((unsigned int)s) << 16);
}
__device__ __forceinline__ float bflo(unsigned int u) { return __uint_as_float(u << 16); }
__device__ __forceinline__ float bfhi(unsigned int u) { return __uint_as_float(u & 0xFFFF0000u); }

// ---------------------------------------------------------------------------
// Tiled node GEMM: 64 nodes/block, thread = 4 nodes x 4 outputs.
// Output table in bf16 (for gather consumers). MODE 1: es/ed head-dot epilogue.
// ---------------------------------------------------------------------------
template<int KIN, int MODE>
__global__ __launch_bounds__(256)
void gemm_tile(const float* __restrict__ in, const float* __restrict__ W,
               bfu* __restrict__ outB,
               const float* __restrict__ a_s, const float* __restrict__ a_d,
               float* __restrict__ es, float* __restrict__ ed)
{
    __shared__ float Ws[KIN * 64];
    __shared__ float rows[64 * (KIN + 1)];
    int t = threadIdx.x;
    int base = blockIdx.x * 64;
    {
        const float4* Wv = (const float4*)W;
        float4* Wsv = (float4*)Ws;
        for (int i = t; i < KIN * 16; i += 256) Wsv[i] = Wv[i];
    }
    constexpr int RQ = KIN / 4;
    for (int i = t; i < 64 * RQ; i += 256) {
        int r = i / RQ, c = (i % RQ) * 4;
        int n = base + r;
        float4 v = make_float4(0.f, 0.f, 0.f, 0.f);
        if (n < N_NODES) v = *(const float4*)(in + (size_t)n * KIN + c);
        float* dp = rows + r * (KIN + 1) + c;
        dp[0] = v.x; dp[1] = v.y; dp[2] = v.z; dp[3] = v.w;
    }
    __syncthreads();
    int tr = t >> 4, tc = t & 15;
    float acc[4][4] = {};
    const float4* Wsv = (const float4*)Ws;
#pragma unroll 8
    for (int k = 0; k < KIN; ++k) {
        float4 w = Wsv[k * 16 + tc];
        float rv[4];
#pragma unroll
        for (int i = 0; i < 4; ++i) rv[i] = rows[(tr * 4 + i) * (KIN + 1) + k];
#pragma unroll
        for (int i = 0; i < 4; ++i) {
            acc[i][0] = fmaf(rv[i], w.x, acc[i][0]);
            acc[i][1] = fmaf(rv[i], w.y, acc[i][1]);
            acc[i][2] = fmaf(rv[i], w.z, acc[i][2]);
            acc[i][3] = fmaf(rv[i], w.w, acc[i][3]);
        }
    }
    int j0 = tc * 4;
#pragma unroll
    for (int i = 0; i < 4; ++i) {
        int n = base + tr * 4 + i;
        if (n < N_NODES) {
            ushort4 ov;
            ov.x = f2bf(acc[i][0]); ov.y = f2bf(acc[i][1]);
            ov.z = f2bf(acc[i][2]); ov.w = f2bf(acc[i][3]);
            *(ushort4*)(outB + (size_t)n * 64 + j0) = ov;
        }
    }
    if (MODE == 1) {
        float s0[4], s1[4];
#pragma unroll
        for (int i = 0; i < 4; ++i) {
            float pes = 0.f, ped = 0.f;
#pragma unroll
            for (int q = 0; q < 4; ++q) {
                pes = fmaf(acc[i][q], a_s[j0 + q], pes);
                ped = fmaf(acc[i][q], a_d[j0 + q], ped);
            }
            pes += __shfl_xor(pes, 1, 64);
            ped += __shfl_xor(ped, 1, 64);
            s0[i] = pes; s1[i] = ped;
        }
        if ((tc & 1) == 0) {
            int h = tc >> 1;
#pragma unroll
            for (int i = 0; i < 4; ++i) {
                int n = base + tr * 4 + i;
                if (n < N_NODES) {
                    es[n * NH + h] = s0[i];
                    ed[n * NH + h] = s1[i];
                }
            }
        }
    }
}

// ---------------------------------------------------------------------------
// Dual node GEMM (shared fp32 input, two weight mats, bf16 outputs).
// SCALED: out_i *= sc_i[n].
// ---------------------------------------------------------------------------
template<int SCALED>
__global__ __launch_bounds__(256)
void gemm_dual(const float* __restrict__ in, const float* __restrict__ W0,
               const float* __restrict__ W1,
               const float* __restrict__ sc0, const float* __restrict__ sc1,
               bfu* __restrict__ out0, bfu* __restrict__ out1)
{
    __shared__ float Ws[2 * 64 * 64];
    __shared__ float rows[64 * 65];
    int t = threadIdx.x;
    int base = blockIdx.x * 64;
    {
        const float4* W0v = (const float4*)W0;
        const float4* W1v = (const float4*)W1;
        float4* Wsv = (float4*)Ws;
        for (int i = t; i < 1024; i += 256) { Wsv[i] = W0v[i]; Wsv[1024 + i] = W1v[i]; }
    }
    for (int i = t; i < 64 * 16; i += 256) {
        int r = i / 16, c = (i % 16) * 4;
        int n = base + r;
        float4 v = make_float4(0.f, 0.f, 0.f, 0.f);
        if (n < N_NODES) v = *(const float4*)(in + (size_t)n * 64 + c);
        float* dp = rows + r * 65 + c;
        dp[0] = v.x; dp[1] = v.y; dp[2] = v.z; dp[3] = v.w;
    }
    __syncthreads();
    int tr = t >> 4, tc = t & 15;
    float a0[4][4] = {}, a1[4][4] = {};
    const float4* Wsv = (const float4*)Ws;
#pragma unroll 4
    for (int k = 0; k < 64; ++k) {
        float4 w0 = Wsv[k * 16 + tc];
        float4 w1 = Wsv[1024 + k * 16 + tc];
        float rv[4];
#pragma unroll
        for (int i = 0; i < 4; ++i) rv[i] = rows[(tr * 4 + i) * 65 + k];
#pragma unroll
        for (int i = 0; i < 4; ++i) {
            a0[i][0] = fmaf(rv[i], w0.x, a0[i][0]);
            a0[i][1] = fmaf(rv[i], w0.y, a0[i][1]);
            a0[i][2] = fmaf(rv[i], w0.z, a0[i][2]);
            a0[i][3] = fmaf(rv[i], w0.w, a0[i][3]);
            a1[i][0] = fmaf(rv[i], w1.x, a1[i][0]);
            a1[i][1] = fmaf(rv[i], w1.y, a1[i][1]);
            a1[i][2] = fmaf(rv[i], w1.z, a1[i][2]);
            a1[i][3] = fmaf(rv[i], w1.w, a1[i][3]);
        }
    }
    int j0 = tc * 4;
#pragma unroll
    for (int i = 0; i < 4; ++i) {
        int n = base + tr * 4 + i;
        if (n >= N_NODES) continue;
        float m0 = 1.f, m1 = 1.f;
        if (SCALED) { m0 = sc0[n]; m1 = sc1[n]; }
        ushort4 o0, o1;
        o0.x = f2bf(a0[i][0] * m0); o0.y = f2bf(a0[i][1] * m0);
        o0.z = f2bf(a0[i][2] * m0); o0.w = f2bf(a0[i][3] * m0);
        o1.x = f2bf(a1[i][0] * m1); o1.y = f2bf(a1[i][1] * m1);
        o1.z = f2bf(a1[i][2] * m1); o1.w = f2bf(a1[i][3] * m1);
        *(ushort4*)(out0 + (size_t)n * 64 + j0) = o0;
        *(ushort4*)(out1 + (size_t)n * 64 + j0) = o1;
    }
}

// ---------------------------------------------------------------------------
// CSR build: histogram -> scan -> scatter (+ dst array)
// ---------------------------------------------------------------------------
__global__ void csr_hist(const int* __restrict__ ei, int* __restrict__ cnt)
{
    int e = blockIdx.x * 256 + threadIdx.x;
    if (e >= E_EDGES) return;
    atomicAdd(&cnt[ei[E_EDGES + e]], 1);
}

__global__ void csr_scan1(const int* __restrict__ cnt, int* __restrict__ offs,
                          int* __restrict__ bsum)
{
    __shared__ int tmp[256];
    int t = threadIdx.x;
    int i = blockIdx.x * 256 + t;
    int v = (i < N_NODES) ? cnt[i] + 1 : 0;
    tmp[t] = v; __syncthreads();
#pragma unroll
    for (int o = 1; o < 256; o <<= 1) {
        int a = (t >= o) ? tmp[t - o] : 0;
        __syncthreads();
        tmp[t] += a;
        __syncthreads();
    }
    if (i < N_NODES) offs[i] = tmp[t] - v;
    if (t == 255) bsum[blockIdx.x] = tmp[255];
}

__global__ void csr_scan2(int* __restrict__ bsum)
{
    __shared__ int tmp[512];
    int t = threadIdx.x;
    int v = (t < NSCAN_BLK) ? bsum[t] : 0;
    tmp[t] = v; __syncthreads();
#pragma unroll
    for (int o = 1; o < 512; o <<= 1) {
        int a = (t >= o) ? tmp[t - o] : 0;
        __syncthreads();
        tmp[t] += a;
        __syncthreads();
    }
    if (t < NSCAN_BLK) bsum[t] = tmp[t] - v;
}

__global__ void csr_scan3(int* __restrict__ offs, const int* __restrict__ bsum,
                          int* __restrict__ cursor)
{
    int i = blockIdx.x * 256 + threadIdx.x;
    if (i < N_NODES) {
        int v = offs[i] + bsum[blockIdx.x];
        offs[i] = v;
        cursor[i] = v;
    }
    if (i == 0) offs[N_NODES] = E2;
}

__global__ void csr_scatter(const int* __restrict__ ei, int* __restrict__ cursor,
                            int* __restrict__ csr, int* __restrict__ csrd)
{
    int e = blockIdx.x * 256 + threadIdx.x;
    if (e >= E2) return;
    int d, tag;
    if (e < E_EDGES) { int s = ei[e]; d = ei[E_EDGES + e]; tag = s; }
    else             { d = e - E_EDGES; tag = d | SELF_FLAG; }
    int pos = atomicAdd(&cursor[d], 1);
    csr[pos] = tag;
    csrd[pos] = d;
}

// ---------------------------------------------------------------------------
// Fused GAT aggregate: wave per dst node; 4 edge-slots x 16 feature-lanes.
// Single pass (no segment-max: logits are O(1), exp(l)/sum(exp(l)) is exact
// up to fp rounding). bf16 feature gather, fp32 accumulate.
// ---------------------------------------------------------------------------
template<int ELU>
__global__ void gat_aggregate4(const int* __restrict__ offs, const int* __restrict__ csr,
                               const float* __restrict__ es, const float* __restrict__ ed,
                               const bfu* __restrict__ hsrcB, const float* __restrict__ bias,
                               float* __restrict__ out)
{
    int n = blockIdx.x * 4 + (threadIdx.x >> 6);
    int lane = threadIdx.x & 63;
    if (n >= N_NODES) return;
    int g  = lane >> 4;        // edge slot 0..3
    int fl = lane & 15;        // feature chunk: features fl*4 .. fl*4+3
    int h  = fl >> 1;          // head
    int beg = offs[n], end = offs[n + 1];
    float edv = ed[n * NH + h];
    float den = 0.f;
    float4 acc = make_float4(0.f, 0.f, 0.f, 0.f);
    for (int p = beg + g; p < end; p += 4) {
        int s = csr[p] & SRC_MASK;
        float l = lrelu(es[s * NH + h] + edv);
        float ex = __expf(l);
        den += ex;
        ushort4 rb = *(const ushort4*)(hsrcB + (size_t)s * HD + fl * 4);
        acc.x = fmaf(bf2f(rb.x), ex, acc.x);
        acc.y = fmaf(bf2f(rb.y), ex, acc.y);
        acc.z = fmaf(bf2f(rb.z), ex, acc.z);
        acc.w = fmaf(bf2f(rb.w), ex, acc.w);
    }
#pragma unroll
    for (int o = 16; o <= 32; o <<= 1) {
        den   += __shfl_xor(den,   o, 64);
        acc.x += __shfl_xor(acc.x, o, 64);
        acc.y += __shfl_xor(acc.y, o, 64);
        acc.z += __shfl_xor(acc.z, o, 64);
        acc.w += __shfl_xor(acc.w, o, 64);
    }
    if (g == 0) {
        float inv = 1.f / (den + 1e-16f);
        float4 bv = *(const float4*)(bias + fl * 4);
        float v0 = acc.x * inv + bv.x;
        float v1 = acc.y * inv + bv.y;
        float v2 = acc.z * inv + bv.z;
        float v3 = acc.w * inv + bv.w;
        if (ELU) {
            v0 = v0 > 0.f ? v0 : (__expf(v0) - 1.f);
            v1 = v1 > 0.f ? v1 : (__expf(v1) - 1.f);
            v2 = v2 > 0.f ? v2 : (__expf(v2) - 1.f);
            v3 = v3 > 0.f ? v3 : (__expf(v3) - 1.f);
        }
        *(float4*)(out + (size_t)n * HD + fl * 4) = make_float4(v0, v1, v2, v3);
    }
}

// ---------------------------------------------------------------------------
// node attention, tiled: 64 nodes/block, w1+rows staged in LDS.
// ---------------------------------------------------------------------------
__global__ __launch_bounds__(256)
void node_att_tile(const float* __restrict__ H, const float* __restrict__ w1,
                   const float* __restrict__ b1, const float* __restrict__ w2,
                   const float* __restrict__ b2, float* __restrict__ ac,
                   float* __restrict__ at)
{
    __shared__ float w1s[64 * 32];
    __shared__ float w2s[64];
    __shared__ float rows[64 * 65];
    int t = threadIdx.x;
    int base = blockIdx.x * 64;
    {
        const float4* w1v = (const float4*)w1;
        float4* dst = (float4*)w1s;
        for (int i = t; i < 512; i += 256) dst[i] = w1v[i];
    }
    if (t < 64) w2s[t] = w2[t];
    for (int i = t; i < 64 * 16; i += 256) {
        int r = i >> 4, c = (i & 15) * 4;
        int n = base + r;
        float4 v = make_float4(0.f, 0.f, 0.f, 0.f);
        if (n < N_NODES) v = *(const float4*)(H + (size_t)n * 64 + c);
        float* dp = rows + r * 65 + c;
        dp[0] = v.x; dp[1] = v.y; dp[2] = v.z; dp[3] = v.w;
    }
    __syncthreads();
    int tr = t >> 3;
    int tc = t & 7;
    float4 bv = *(const float4*)(b1 + tc * 4);
    float4 acc0 = bv, acc1 = bv;
    const float4* w1sv = (const float4*)w1s;
#pragma unroll 8
    for (int k = 0; k < 64; ++k) {
        float4 w = w1sv[k * 8 + tc];
        float r0 = rows[tr * 65 + k];
        float r1 = rows[(tr + 32) * 65 + k];
        acc0.x = fmaf(r0, w.x, acc0.x); acc0.y = fmaf(r0, w.y, acc0.y);
        acc0.z = fmaf(r0, w.z, acc0.z); acc0.w = fmaf(r0, w.w, acc0.w);
        acc1.x = fmaf(r1, w.x, acc1.x); acc1.y = fmaf(r1, w.y, acc1.y);
        acc1.z = fmaf(r1, w.z, acc1.z); acc1.w = fmaf(r1, w.w, acc1.w);
    }
    float z00 = 0.f, z01 = 0.f, z10 = 0.f, z11 = 0.f;
    float h0, w20, w21;
    int j0 = tc * 4;
#pragma unroll
    for (int q = 0; q < 4; ++q) {
        float a0q = q == 0 ? acc0.x : q == 1 ? acc0.y : q == 2 ? acc0.z : acc0.w;
        float a1q = q == 0 ? acc1.x : q == 1 ? acc1.y : q == 2 ? acc1.z : acc1.w;
        w20 = w2s[(j0 + q) * 2]; w21 = w2s[(j0 + q) * 2 + 1];
        h0 = fmaxf(a0q, 0.f);
        z00 = fmaf(h0, w20, z00); z01 = fmaf(h0, w21, z01);
        h0 = fmaxf(a1q, 0.f);
        z10 = fmaf(h0, w20, z10); z11 = fmaf(h0, w21, z11);
    }
#pragma unroll
    for (int o = 1; o < 8; o <<= 1) {
        z00 += __shfl_xor(z00, o, 64); z01 += __shfl_xor(z01, o, 64);
        z10 += __shfl_xor(z10, o, 64); z11 += __shfl_xor(z11, o, 64);
    }
    if (tc == 0) {
        int n0 = base + tr, n1 = base + tr + 32;
        if (n0 < N_NODES) {
            float zz0 = z00 + b2[0], zz1 = z01 + b2[1];
            float mx = fmaxf(zz0, zz1);
            float e0 = __expf(zz0 - mx), e1 = __expf(zz1 - mx);
            float ss = e0 + e1;
            ac[n0] = e0 / ss; at[n0] = e1 / ss;
        }
        if (n1 < N_NODES) {
            float zz0 = z10 + b2[0], zz1 = z11 + b2[1];
            float mx = fmaxf(zz0, zz1);
            float e0 = __expf(zz0 - mx), e1 = __expf(zz1 - mx);
            float ss = e0 + e1;
            ac[n1] = e0 / ss; at[n1] = e1 / ss;
        }
    }
}

// ---------------------------------------------------------------------------
// edge attention, flat over CSR positions: 8 lanes/edge, bf16 P1/P2 gather
// ---------------------------------------------------------------------------
__global__ __launch_bounds__(256)
void edge_att_flat(const int* __restrict__ csr, const int* __restrict__ csrd,
                   const bfu* __restrict__ P1b, const bfu* __restrict__ P2b,
                   const float* __restrict__ b1, const float* __restrict__ w2,
                   const float* __restrict__ b2,
                   float* __restrict__ bc, float* __restrict__ bt)
{
    int lane = threadIdx.x & 63;
    int sg = lane >> 3, q = lane & 7;
    int p = (blockIdx.x * 4 + (threadIdx.x >> 6)) * 8 + sg;
    if (p >= E2) return;
    int sv = csr[p];
    if (sv & SELF_FLAG) return;
    int d = csrd[p];
    uint4 U1 = *(const uint4*)(P1b + (size_t)sv * 64 + q * 8);
    uint4 U2 = *(const uint4*)(P2b + (size_t)d  * 64 + q * 8);
    const float4* pb = (const float4*)(b1 + q * 8);
    const float4* pw = (const float4*)(w2 + q * 16);
    float4 c0 = pb[0], c1 = pb[1];
    float4 w0 = pw[0], w1v = pw[1], w2v = pw[2], w3v = pw[3];
    float h0 = fmaxf(bflo(U1.x) + bflo(U2.x) + c0.x, 0.f);
    float h1 = fmaxf(bfhi(U1.x) + bfhi(U2.x) + c0.y, 0.f);
    float h2 = fmaxf(bflo(U1.y) + bflo(U2.y) + c0.z, 0.f);
    float h3 = fmaxf(bfhi(U1.y) + bfhi(U2.y) + c0.w, 0.f);
    float h4 = fmaxf(bflo(U1.z) + bflo(U2.z) + c1.x, 0.f);
    float h5 = fmaxf(bfhi(U1.z) + bfhi(U2.z) + c1.y, 0.f);
    float h6 = fmaxf(bflo(U1.w) + bflo(U2.w) + c1.z, 0.f);
    float h7 = fmaxf(bfhi(U1.w) + bfhi(U2.w) + c1.w, 0.f);
    float z0 = h0 * w0.x + h1 * w0.z + h2 * w1v.x + h3 * w1v.z
             + h4 * w2v.x + h5 * w2v.z + h6 * w3v.x + h7 * w3v.z;
    float z1 = h0 * w0.y + h1 * w0.w + h2 * w1v.y + h3 * w1v.w
             + h4 * w2v.y + h5 * w2v.w + h6 * w3v.y + h7 * w3v.w;
    z0 += __shfl_xor(z0, 1, 64); z1 += __shfl_xor(z1, 1, 64);
    z0 += __shfl_xor(z0, 2, 64); z1 += __shfl_xor(z1, 2, 64);
    z0 += __shfl_xor(z0, 4, 64); z1 += __shfl_xor(z1, 4, 64);
    if (q == 0) {
        z0 += b2[0]; z1 += b2[1];
        float mx = fmaxf(z0, z1);
        float e0 = __expf(z0 - mx), e1 = __expf(z1 - mx);
        float ss = e0 + e1;
        bc[p] = e0 / ss;
        bt[p] = e1 / ss;
    }
}

// ---------------------------------------------------------------------------
// GCN: degree+rsqrt, flat per-edge norm precompute, dual gather aggregate
// ---------------------------------------------------------------------------
__global__ void gcn_deg_dis(const int* __restrict__ offs, const int* __restrict__ csr,
                            const float* __restrict__ bc, const float* __restrict__ bt,
                            float* __restrict__ disc, float* __restrict__ dist)
{
    int n = blockIdx.x * 256 + threadIdx.x;
    if (n >= N_NODES) return;
    int beg = offs[n], end = offs[n + 1];
    float dc = 0.f, dt = 0.f;
    for (int p = beg; p < end; ++p) {
        if (csr[p] & SELF_FLAG) { dc += 1.f; dt += 1.f; }
        else { dc += bc[p]; dt += bt[p]; }
    }
    disc[n] = dc > 0.f ? rsqrtf(fmaxf(dc, 1e-20f)) : 0.f;
    dist[n] = dt > 0.f ? rsqrtf(fmaxf(dt, 1e-20f)) : 0.f;
}

__global__ void gcn_norm(const int* __restrict__ csr, const int* __restrict__ csrd,
                         const float* __restrict__ disc, const float* __restrict__ dist,
                         float* __restrict__ bc, float* __restrict__ bt)
{
    int p = blockIdx.x * 256 + threadIdx.x;
    if (p >= E2) return;
    int sv = csr[p];
    int s = sv & SRC_MASK;
    int d = csrd[p];
    float wc, wt;
    if (sv & SELF_FLAG) { wc = 1.f; wt = 1.f; }
    else { wc = bc[p]; wt = bt[p]; }
    bc[p] = disc[s] * wc * disc[d];
    bt[p] = dist[s] * wt * dist[d];
}

__global__ void gcn_aggregate_both(const int* __restrict__ offs, const int* __restrict__ csr,
                                   const bfu* __restrict__ preC, const bfu* __restrict__ preT,
                                   const float* __restrict__ nrmC, const float* __restrict__ nrmT,
                                   float* __restrict__ outC, float* __restrict__ outT)
{
    int n = blockIdx.x * 4 + (threadIdx.x >> 6);
    int lane = threadIdx.x & 63;
    if (n >= N_NODES) return;
    int g  = lane >> 4;
    int fl = lane & 15;
    int beg = offs[n], end = offs[n + 1];
    float4 a1 = make_float4(0.f, 0.f, 0.f, 0.f);
    float4 a2 = make_float4(0.f, 0.f, 0.f, 0.f);
    for (int p = beg + g; p < end; p += 4) {
        int s = csr[p] & SRC_MASK;
        float wc = nrmC[p], wt = nrmT[p];
        ushort4 rc = *(const ushort4*)(preC + (size_t)s * HD + fl * 4);
        ushort4 rt = *(const ushort4*)(preT + (size_t)s * HD + fl * 4);
        a1.x = fmaf(bf2f(rc.x), wc, a1.x);
        a1.y = fmaf(bf2f(rc.y), wc, a1.y);
        a1.z = fmaf(bf2f(rc.z), wc, a1.z);
        a1.w = fmaf(bf2f(rc.w), wc, a1.w);
        a2.x = fmaf(bf2f(rt.x), wt, a2.x);
        a2.y = fmaf(bf2f(rt.y), wt, a2.y);
        a2.z = fmaf(bf2f(rt.z), wt, a2.z);
        a2.w = fmaf(bf2f(rt.w), wt, a2.w);
    }
#pragma unroll
    for (int o = 16; o <= 32; o <<= 1) {
        a1.x += __shfl_xor(a1.x, o, 64); a1.y += __shfl_xor(a1.y, o, 64);
        a1.z += __shfl_xor(a1.z, o, 64); a1.w += __shfl_xor(a1.w, o, 64);
        a2.x += __shfl_xor(a2.x, o, 64); a2.y += __shfl_xor(a2.y, o, 64);
        a2.z += __shfl_xor(a2.z, o, 64); a2.w += __shfl_xor(a2.w, o, 64);
    }
    if (g == 0) {
        *(float4*)(outC + (size_t)n * HD + fl * 4) = a1;
        *(float4*)(outT + (size_t)n * HD + fl * 4) = a2;
    }
}

// ---------------------------------------------------------------------------
// readout (both branches): segment sum of rows by sorted `batch`
// ---------------------------------------------------------------------------
__global__ void readout_both(const float* __restrict__ Gc, const float* __restrict__ Gt,
                             const int* __restrict__ batch,
                             float* __restrict__ S_c, float* __restrict__ S_t,
                             float* __restrict__ cnt)
{
    int chunk = blockIdx.x * 4 + (threadIdx.x >> 6);
    int lane = threadIdx.x & 63;
    int n0 = chunk * 128;
    if (n0 >= N_NODES) return;
    int n1 = n0 + 128; if (n1 > N_NODES) n1 = N_NODES;
    int gp = batch[n0];
    float a1 = 0.f, a2 = 0.f; int rc = 0;
    for (int n = n0; n < n1; ++n) {
        int g = batch[n];
        if (g != gp) {
            atomicAdd(&S_c[gp * 64 + lane], a1);
            atomicAdd(&S_t[gp * 64 + lane], a2);
            if (lane == 0) atomicAdd(&cnt[gp], (float)rc);
            a1 = a2 = 0.f; rc = 0; gp = g;
        }
        a1 += Gc[(size_t)n * 64 + lane];
        a2 += Gt[(size_t)n * 64 + lane];
        ++rc;
    }
    atomicAdd(&S_c[gp * 64 + lane], a1);
    atomicAdd(&S_t[gp * 64 + lane], a2);
    if (lane == 0) atomicAdd(&cnt[gp], (float)rc);
}

// ---------------------------------------------------------------------------
// final per-graph heads
// ---------------------------------------------------------------------------
__global__ void final_head(const float* __restrict__ S_c, const float* __restrict__ S_t,
                           const float* __restrict__ cnt,
                           const float* __restrict__ gc_b, const float* __restrict__ gt_b,
                           const float* __restrict__ rc_w, const float* __restrict__ rc_b,
                           const float* __restrict__ rt_w, const float* __restrict__ rt_b,
                           const float* __restrict__ cc_w1, const float* __restrict__ cc_b1,
                           const float* __restrict__ cc_w2, const float* __restrict__ cc_b2,
                           const float* __restrict__ ct_w1, const float* __restrict__ ct_b1,
                           const float* __restrict__ ct_w2, const float* __restrict__ ct_b2,
                           const float* __restrict__ cm_w1, const float* __restrict__ cm_b1,
                           const float* __restrict__ cm_w2, const float* __restrict__ cm_b2,
                           float* __restrict__ out)
{
    int g = blockIdx.x;
    int j = threadIdx.x;
    __shared__ float sc[64], st[64], hgc[64], hgt[64], hid[64];
    float c = cnt[g];
    sc[j] = S_c[g * 64 + j] + c * gc_b[j];
    st[j] = S_t[g * 64 + j] + c * gt_b[j];
    __syncthreads();
    float acr = c * rc_b[j], atr = c * rt_b[j];
#pragma unroll 8
    for (int k = 0; k < 64; ++k) {
        acr = fmaf(sc[k], rc_w[k * 64 + j], acr);
        atr = fmaf(st[k], rt_w[k * 64 + j], atr);
    }
    hgc[j] = acr; hgt[j] = atr;
    out[3840 + g * 64 + j]  = acr;
    out[12032 + g * 64 + j] = atr;
    __syncthreads();
    float hv = 0.f;
    if (j < 32) {
        float a = cc_b1[j];
#pragma unroll 8
        for (int k = 0; k < 64; ++k) a = fmaf(hgc[k], cc_w1[k * 32 + j], a);
        hv = fmaxf(a, 0.f);
    }
    hid[j] = hv;
    __syncthreads();
    if (j < NC) {
        float a = cc_b2[j];
#pragma unroll
        for (int k = 0; k < 32; ++k) a = fmaf(hid[k], cc_w2[k * NC + j], a);
        out[g * NC + j] = a;
    }
    __syncthreads();
    hv = 0.f;
    if (j < 32) {
        float a = ct_b1[j];
#pragma unroll 8
        for (int k = 0; k < 64; ++k) a = fmaf(hgt[k], ct_w1[k * 32 + j], a);
        hv = fmaxf(a, 0.f);
    }
    hid[j] = hv;
    __syncthreads();
    if (j < NC) {
        float a = ct_b2[j];
#pragma unroll
        for (int k = 0; k < 32; ++k) a = fmaf(hid[k], ct_w2[k * NC + j], a);
        out[1280 + g * NC + j] = a;
    }
    __syncthreads();
    {
        float a = cm_b1[j];
#pragma unroll 8
        for (int k = 0; k < 64; ++k) {
            a = fmaf(hgc[k], cm_w1[k * 64 + j], a);
            a = fmaf(hgt[k], cm_w1[(64 + k) * 64 + j], a);
        }
        hid[j] = fmaxf(a, 0.f);
    }
    __syncthreads();
    if (j < NC) {
        float a = cm_b2[j];
#pragma unroll 8
        for (int k = 0; k < 64; ++k) a = fmaf(hid[k], cm_w2[k * NC + j], a);
        out[2560 + g * NC + j] = a;
    }
}

// ---------------------------------------------------------------------------
extern "C" void kernel_launch(void* const* d_in, const int* in_sizes, int n_in,
                              void* d_out, int out_size, void* d_ws, size_t ws_size,
                              hipStream_t stream)
{
    const float* x     = (const float*)d_in[0];
    const int*   ei    = (const int*)d_in[1];
    const int*   batch = (const int*)d_in[2];
    const float* W1    = (const float*)d_in[3];
    const float* as1   = (const float*)d_in[4];
    const float* ad1   = (const float*)d_in[5];
    const float* b1    = (const float*)d_in[6];
    const float* W2    = (const float*)d_in[7];
    const float* as2   = (const float*)d_in[8];
    const float* ad2   = (const float*)d_in[9];
    const float* b2    = (const float*)d_in[10];
    const float* na_w1 = (const float*)d_in[11];
    const float* na_b1 = (const float*)d_in[12];
    const float* na_w2 = (const float*)d_in[13];
    const float* na_b2 = (const float*)d_in[14];
    const float* ea_w1 = (const float*)d_in[15];
    const float* ea_b1 = (const float*)d_in[16];
    const float* ea_w2 = (const float*)d_in[17];
    const float* ea_b2 = (const float*)d_in[18];
    const float* gc_w  = (const float*)d_in[19];
    const float* gc_b  = (const float*)d_in[20];
    const float* gt_w  = (const float*)d_in[21];
    const float* gt_b  = (const float*)d_in[22];
    const float* rc_w  = (const float*)d_in[23];
    const float* rc_b  = (const float*)d_in[24];
    const float* rt_w  = (const float*)d_in[25];
    const float* rt_b  = (const float*)d_in[26];
    const float* cc_w1 = (const float*)d_in[27];
    const float* cc_b1 = (const float*)d_in[28];
    const float* cc_w2 = (const float*)d_in[29];
    const float* cc_b2 = (const float*)d_in[30];
    const float* ct_w1 = (const float*)d_in[31];
    const float* ct_b1 = (const float*)d_in[32];
    const float* ct_w2 = (const float*)d_in[33];
    const float* ct_b2 = (const float*)d_in[34];
    const float* cm_w1 = (const float*)d_in[35];
    const float* cm_b1 = (const float*)d_in[36];
    const float* cm_w2 = (const float*)d_in[37];
    const float* cm_b2 = (const float*)d_in[38];
    float* out = (float*)d_out;

    float* ws = (float*)d_ws;
    size_t o = 0;
    const size_t nf = (size_t)N_NODES * HD;
    float* T1   = ws + o; o += nf;             // H1 / Gc-agg out
    float* T2   = ws + o; o += nf;             // H  / Gt-agg out
    float* es   = ws + o; o += (size_t)N_NODES * NH;
    float* ed   = ws + o; o += (size_t)N_NODES * NH;
    float* ac   = ws + o; o += N_NODES;
    float* at   = ws + o; o += N_NODES;
    float* bc   = ws + o; o += E2;             // beta_c -> norm_c (in place)
    float* bt   = ws + o; o += E2;             // beta_t -> norm_t (in place)
    float* degc = ws + o; o += N_NODES;
    float* degt = ws + o; o += N_NODES;
    float* S_c  = ws + o; o += NG * 64;
    float* S_t  = ws + o; o += NG * 64;
    float* cntf = ws + o; o += NG;
    bfu* B0     = (bfu*)(ws + o); o += nf / 2; // bf16 gather table (reused 3x)
    bfu* B1     = (bfu*)(ws + o); o += nf / 2; // bf16 gather table (reused 2x)
    int* csr    = (int*)(ws + o); o += E2;
    int* csrd   = (int*)(ws + o); o += E2;
    int* offs   = (int*)(ws + o); o += N_NODES + 1;
    int* cnt    = (int*)at;
    int* cursor = (int*)ac;
    int* bsum   = (int*)degc;

    const int NW_BLKS = N_NODES / 4;             // 25000
    const int NT_BLKS = (N_NODES + 255) / 256;   // 391
    const int E_BLKS  = (E2 + 255) / 256;        // 3516
    const int EF_BLKS = (E2 + 31) / 32;          // 28125
    const int RO_BLKS = ((N_NODES + 127) / 128 + 3) / 4;  // 196

    // ---------------- CSR build ----------------
    hipMemsetAsync(cnt, 0, (size_t)N_NODES * 4, stream);
    csr_hist<<<(E_EDGES + 255) / 256, 256, 0, stream>>>(ei, cnt);
    csr_scan1<<<NSCAN_BLK, 256, 0, stream>>>(cnt, offs, bsum);
    csr_scan2<<<1, 512, 0, stream>>>(bsum);
    csr_scan3<<<NSCAN_BLK, 256, 0, stream>>>(offs, bsum, cursor);
    csr_scatter<<<E_BLKS, 256, 0, stream>>>(ei, cursor, csr, csrd);

    // ---------------- GAT layer 1 ----------------
    gemm_tile<FIN, 1><<<NBLK64, 256, 0, stream>>>(x, W1, B0, as1, ad1, es, ed);
    gat_aggregate4<1><<<NW_BLKS, 256, 0, stream>>>(offs, csr, es, ed, B0, b1, T1);

    // ---------------- GAT layer 2 ----------------
    gemm_tile<64, 1><<<NBLK64, 256, 0, stream>>>(T1, W2, B0, as2, ad2, es, ed);
    gat_aggregate4<0><<<NW_BLKS, 256, 0, stream>>>(offs, csr, es, ed, B0, b2, T2);

    // ---------------- node attention ----------------
    node_att_tile<<<NBLK64, 256, 0, stream>>>(T2, na_w1, na_b1, na_w2, na_b2, ac, at);

    // ---------------- edge attention (P1 -> B0, P2 -> B1, bf16) -------------
    gemm_dual<0><<<NBLK64, 256, 0, stream>>>(T2, ea_w1, ea_w1 + 64 * 64,
                                             nullptr, nullptr, B0, B1);
    edge_att_flat<<<EF_BLKS, 256, 0, stream>>>(csr, csrd, B0, B1, ea_b1, ea_w2, ea_b2, bc, bt);

    // ---------------- GCN norm (bc/bt -> per-edge norms in place) -----------
    gcn_deg_dis<<<NT_BLKS, 256, 0, stream>>>(offs, csr, bc, bt, degc, degt);
    gcn_norm<<<E_BLKS, 256, 0, stream>>>(csr, csrd, degc, degt, bc, bt);

    hipMemsetAsync(S_c, 0, (size_t)(2 * NG * 64 + NG) * 4, stream);

    // ---------------- GCN pre-transforms (pre_c -> B0, pre_t -> B1) ---------
    gemm_dual<1><<<NBLK64, 256, 0, stream>>>(T2, gc_w, gt_w, ac, at, B0, B1);

    // ---------------- GCN aggregate (both) + readout ------------------------
    gcn_aggregate_both<<<NW_BLKS, 256, 0, stream>>>(offs, csr, B0, B1, bc, bt, T1, T2);
    readout_both<<<RO_BLKS, 256, 0, stream>>>(T1, T2, batch, S_c, S_t, cntf);

    // ---------------- heads ----------------
    final_head<<<NG, 64, 0, stream>>>(S_c, S_t, cntf,
                                      gc_b, gt_b, rc_w, rc_b, rt_w, rt_b,
                                      cc_w1, cc_b1, cc_w2, cc_b2,
                                      ct_w1, ct_b1, ct_w2, ct_b2,
                                      cm_w1, cm_b1, cm_w2, cm_b2, out);
    (void)in_sizes; (void)n_in; (void)out_size; (void)ws_size;
}